// Round 10
// baseline (366.556 us; speedup 1.0000x reference)
//
#include <hip/hip_runtime.h>
#include <math.h>

// Non-local attention: X [8, 64, 64, 64] fp32.
// Per batch b: Q=K=V = X_b^T  [S=4096, D=64];  out = softmax(Q K^T) V, stored [b][c][s].
//
// R20: split-K x8 on the R13 structure (the measured-best loop: barrier-free,
// LDS-free, per-wave global fragment loads, 64 Q rows/wave, reg-double-buffered K).
// Nine rounds established: no pipe is saturated (MfmaUtil ~30%, VALUBusy ~38%,
// HBM ~5%) -- the kernel is per-wave CHAIN-latency-bound: wall ~= niter x chain
// (~1200 cyc: loads->S->exp->pack->PV), and splitK4 @ 64 rows/wave fixes total
// waves at 2048 = 2/SIMD, too few to overlap chains. In this regime halving niter
// per wave halves wall time if the extra waves are co-resident. So: splitK 4->8,
// niter 16, grid 2048 (8 blocks/CU), launch_bounds(128,3) (VGPR cap 170, ~3-4
// waves/SIMD). Supporting edits: two-phase epilogue shrinks sO LDS 34KB->17.4KB
// (9 blocks/CU by LDS); combine sums 8 partial slabs. Loop body/prepass/layouts/
// XCD pinning byte-identical to R13. Final K over-read (1 tile) lands at Vf start,
// inside d_ws, values unused.
//
// Kf[b][tile][mt][ks][lane]: scaled bf16, lane(=quad*16+l15) holds
//   XbfT_scaled[tile*32+mt*16+l15][quad*8+32*ks .. +8]   (also serves Q fragments)
// Vf[b][tile][ct][lane][j]: unscaled bf16, element j at lane (l15,q) holds
//   XbfT[tile*32 + 16*(j>>2) + 4*q + (j&3)][16*ct + l15]   (permuted B-frag order)

#define SEQ 4096
#define DIM 64
#define LDB 72
#define LDO 68
#define LDS2 68
#define QSCALE 1.2011224087864498f   // sqrt(log2(e))

typedef __attribute__((ext_vector_type(8))) short  short8;
typedef __attribute__((ext_vector_type(4))) float  f32x4;

__device__ __forceinline__ unsigned short f2bf(float f) {
    union { float f; unsigned int u; } x; x.f = f;
    unsigned int u = x.u + 0x7FFFu + ((x.u >> 16) & 1u);
    return (unsigned short)(u >> 16);
}
__device__ __forceinline__ float bf2f(unsigned short h) {
    union { unsigned int u; float f; } x; x.u = ((unsigned int)h) << 16; return x.f;
}
__device__ __forceinline__ float fast_exp2(float x) {
#if __has_builtin(__builtin_amdgcn_exp2f)
    return __builtin_amdgcn_exp2f(x);
#else
    float r;
    asm("v_exp_f32 %0, %1\n\ts_nop 0" : "=v"(r) : "v"(x));
    return r;
#endif
}
__device__ __forceinline__ float fast_rcp(float x) {
#if __has_builtin(__builtin_amdgcn_rcpf)
    return __builtin_amdgcn_rcpf(x);
#else
    return 1.f / x;
#endif
}

// ---------------- prepass: fragment-order bf16 arrays + scaled norms + max partials ----
__global__ __launch_bounds__(256) void prepass4(const float* __restrict__ X,
                                                unsigned short* __restrict__ Kf,
                                                unsigned short* __restrict__ Vf,
                                                float* __restrict__ Norms,
                                                float* __restrict__ MaxPart) {
    __shared__ __align__(16) unsigned short sT[64 * LDS2];    // scaled [m][c]
    __shared__ __align__(16) unsigned short sVu[64 * LDS2];   // unscaled [c][m]
    __shared__ float sRed[4];
    const int b = blockIdx.y, m0 = blockIdx.x * 64;
    const float* Xb = X + (size_t)b * DIM * SEQ;
    const int t = threadIdx.x, w = t >> 6;
    const int mw = t & 15, cg = t >> 4;

    #pragma unroll
    for (int cr = 0; cr < 4; ++cr) {
        const int c = cg * 4 + cr;
        const f32x4 v = *(const f32x4*)(Xb + (size_t)c * SEQ + m0 + 4 * mw);
        *(ushort4*)(sVu + c * LDS2 + 4 * mw) =
            make_ushort4(f2bf(v.x), f2bf(v.y), f2bf(v.z), f2bf(v.w));
        sT[(4 * mw + 0) * LDS2 + c] = f2bf(v.x * QSCALE);
        sT[(4 * mw + 1) * LDS2 + c] = f2bf(v.y * QSCALE);
        sT[(4 * mw + 2) * LDS2 + c] = f2bf(v.z * QSCALE);
        sT[(4 * mw + 3) * LDS2 + c] = f2bf(v.w * QSCALE);
    }
    __syncthreads();
    const int m = t >> 2, ck = t & 3;   // Kf mapping: key row m, dim-chunk pair ck

    // ---- Kf: row m, dim-chunks 2ck and 2ck+1 ----
    const short8 a0 = *(const short8*)(sT + m * LDS2 + ck * 16);
    const short8 a1 = *(const short8*)(sT + m * LDS2 + ck * 16 + 8);
    {
        const size_t base = (size_t)b * 262144 + (size_t)(m0 >> 5) * 2048;  // shorts
        #pragma unroll
        for (int j = 0; j < 2; ++j) {
            const int chunk = 2 * ck + j;
            const int tile = m >> 5, mt = (m >> 4) & 1;
            const int quad = chunk & 3, ks = chunk >> 2;
            const size_t off = base + (size_t)(tile * 4 + mt * 2 + ks) * 512
                                    + (size_t)(quad * 16 + (m & 15)) * 8;
            *(short8*)(Kf + off) = j ? a1 : a0;
        }
    }
    // ---- scaled row norm (from a0/a1), exact C-S bound on scaled scores ----
    float s = 0.f;
    #pragma unroll
    for (int i = 0; i < 8; ++i) {
        const float f0 = bf2f((unsigned short)a0[i]);
        const float f1 = bf2f((unsigned short)a1[i]);
        s += f0 * f0 + f1 * f1;
    }
    s += __shfl_xor(s, 1);
    s += __shfl_xor(s, 2);
    const float nm = sqrtf(s);
    if (ck == 0) Norms[(size_t)b * SEQ + m0 + m] = nm;

    // ---- Vf: permuted B-frag order, one contiguous 16B fragment per (tile,ct,lane) ----
    {
        const int ctv = (t >> 6) & 3, lv = t & 63;
        const int qv = lv >> 4, l15v = lv & 15;
        const int cidx = (16 * ctv + l15v) * LDS2;
        const size_t vbase = (size_t)b * 262144 + (size_t)(m0 >> 5) * 2048
                           + (size_t)ctv * 512 + (size_t)lv * 8;
        #pragma unroll
        for (int tl = 0; tl < 2; ++tl) {
            const ushort4 g0 = *(const ushort4*)(sVu + cidx + tl * 32 + 4 * qv);
            const ushort4 g1 = *(const ushort4*)(sVu + cidx + tl * 32 + 16 + 4 * qv);
            union { ushort4 g[2]; short8 v; } cat;
            cat.g[0] = g0; cat.g[1] = g1;
            *(short8*)(Vf + vbase + (size_t)tl * 2048) = cat.v;
        }
    }

    float mx = nm;
    #pragma unroll
    for (int d = 4; d < 64; d <<= 1) mx = fmaxf(mx, __shfl_xor(mx, d));
    if ((t & 63) == 0) sRed[w] = mx;
    __syncthreads();
    if (t == 0)
        MaxPart[b * 64 + blockIdx.x] =
            fmaxf(fmaxf(sRed[0], sRed[1]), fmaxf(sRed[2], sRed[3]));
}

// ---- per-iteration macros for the flash loop (kp/vp/qf/cin/acc_o/lp4 in scope) ----
#define LOADK(DST)                                                                 \
    {                                                                              \
        _Pragma("unroll")                                                          \
        for (int mt_ = 0; mt_ < 2; ++mt_) {                                        \
            _Pragma("unroll")                                                      \
            for (int ks_ = 0; ks_ < 2; ++ks_)                                      \
                DST[mt_][ks_] = *(const short8*)(kp + (mt_ * 2 + ks_) * 512);      \
        }                                                                          \
    }

#define LOADV(DST)                                                                 \
    {                                                                              \
        _Pragma("unroll")                                                          \
        for (int ct_ = 0; ct_ < 4; ++ct_)                                          \
            DST[ct_] = *(const short8*)(vp + ct_ * 512);                           \
    }

#define ATTN_STEP(KF, VF)                                                          \
    {                                                                              \
        f32x4 a_[4][2];                                                            \
        _Pragma("unroll")                                                          \
        for (int qt_ = 0; qt_ < 4; ++qt_) {                                        \
            _Pragma("unroll")                                                      \
            for (int mt_ = 0; mt_ < 2; ++mt_) {                                    \
                f32x4 s_ = cin[qt_];                                               \
                s_ = __builtin_amdgcn_mfma_f32_16x16x32_bf16(KF[mt_][0], qf[qt_][0], s_, 0, 0, 0); \
                s_ = __builtin_amdgcn_mfma_f32_16x16x32_bf16(KF[mt_][1], qf[qt_][1], s_, 0, 0, 0); \
                a_[qt_][mt_] = s_;                                                 \
            }                                                                      \
        }                                                                          \
        short8 pa_[4];                                                             \
        _Pragma("unroll")                                                          \
        for (int qt_ = 0; qt_ < 4; ++qt_) {                                        \
            union { unsigned u[4]; short8 v; } pk_;                                \
            _Pragma("unroll")                                                      \
            for (int mt_ = 0; mt_ < 2; ++mt_) {                                    \
                const float p0_ = fast_exp2(a_[qt_][mt_][0]);                      \
                const float p1_ = fast_exp2(a_[qt_][mt_][1]);                      \
                const float p2_ = fast_exp2(a_[qt_][mt_][2]);                      \
                const float p3_ = fast_exp2(a_[qt_][mt_][3]);                      \
                lp4[qt_] += (f32x4){p0_, p1_, p2_, p3_};                           \
                pk_.u[2 * mt_ + 0] = __builtin_amdgcn_perm(__float_as_uint(p1_), __float_as_uint(p0_), 0x07060302u); \
                pk_.u[2 * mt_ + 1] = __builtin_amdgcn_perm(__float_as_uint(p3_), __float_as_uint(p2_), 0x07060302u); \
            }                                                                      \
            pa_[qt_] = pk_.v;                                                      \
        }                                                                          \
        _Pragma("unroll")                                                          \
        for (int qt_ = 0; qt_ < 4; ++qt_) {                                        \
            _Pragma("unroll")                                                      \
            for (int ct_ = 0; ct_ < 4; ++ct_)                                      \
                acc_o[qt_][ct_] = __builtin_amdgcn_mfma_f32_16x16x32_bf16(pa_[qt_], VF[ct_], acc_o[qt_][ct_], 0, 0, 0); \
        }                                                                          \
    }

// Flash kernel: 2 waves x 64 Q rows, split-K x8, fragment-order global K/V,
// LDS-free inner loop (P feeds PV directly from registers at K=32).
template <bool PARTIAL>
__global__ __launch_bounds__(128, 3) void attn_split4(const unsigned short* __restrict__ Kf,
                                                      const unsigned short* __restrict__ Vf,
                                                      const float* __restrict__ Norms,
                                                      const float* __restrict__ MaxPart,
                                                      unsigned short* __restrict__ Obf,  // PARTIAL
                                                      float* __restrict__ Lbase,         // PARTIAL
                                                      float* __restrict__ Out,           // !PARTIAL
                                                      int niter) {
    __shared__ __align__(16) float sO[64 * LDO];   // two-phase epilogue buffer (17408 B)

    const int tid  = threadIdx.x;
    const int lane = tid & 63;
    const int w    = tid >> 6;
    const int l15  = lane & 15;
    const int quad = lane >> 4;

    // XCD-pinned work remap: dispatch round-robins linear wg id across the 8 XCDs,
    // so gid&7 == XCD. Assign batch = gid&7 so each XCD streams exactly one batch's
    // slabs (L2-resident). Pure work remap -- placement only affects speed.
    const int gid  = blockIdx.x + 32 * (blockIdx.y + 8 * blockIdx.z);
    const int b    = gid & 7;
    const int rest = gid >> 3;             // 0..255
    const int s0   = (rest & 31) * 128;    // 128 Q rows per block
    const int h    = rest >> 5;            // 0..7 split-K eighth
    const int kt0  = h * niter;
    const unsigned short* Kfb = Kf + (size_t)b * 262144;
    const unsigned short* Vfb = Vf + (size_t)b * 262144;

    float mxn = MaxPart[b * 64 + lane];
    #pragma unroll
    for (int d = 1; d < 64; d <<= 1) mxn = fmaxf(mxn, __shfl_xor(mxn, d));

    // Q frags from Kf (scaled): wave w owns rows s0+64w .. +63 (qt = 0..3)
    short8 qf[4][2];
    f32x4 cin[4];
    const int qtile = (s0 + 64 * w) >> 5;
    #pragma unroll
    for (int qt = 0; qt < 4; ++qt) {
        #pragma unroll
        for (int ks = 0; ks < 2; ++ks)
            qf[qt][ks] = *(const short8*)(Kfb
                + (size_t)((qtile + (qt >> 1)) * 4 + (qt & 1) * 2 + ks) * 512 + lane * 8);
        const float mrow = Norms[(size_t)b * SEQ + s0 + 64 * w + 16 * qt + l15] * mxn;
        cin[qt] = (f32x4){-mrow, -mrow, -mrow, -mrow};
    }

    f32x4 acc_o[4][4];
    #pragma unroll
    for (int qt = 0; qt < 4; ++qt)
        #pragma unroll
        for (int ct = 0; ct < 4; ++ct) acc_o[qt][ct] = (f32x4){0.f, 0.f, 0.f, 0.f};
    f32x4 lp4[4];
    #pragma unroll
    for (int qt = 0; qt < 4; ++qt) lp4[qt] = (f32x4){0.f, 0.f, 0.f, 0.f};

    // ---- fragment stream pointers (lane-contiguous 1KB per 16B-load) ----
    const unsigned short* kp = Kfb + (size_t)kt0 * 2048 + lane * 8;
    const unsigned short* vp = Vfb + (size_t)kt0 * 2048 + lane * 8;

    short8 kA[2][2], kB[2][2];
    LOADK(kA);
    kp += 2048;

    for (int it = 0; it < niter; it += 2) {
        short8 vfA[4];
        LOADV(vfA); vp += 2048;
        LOADK(kB);  kp += 2048;          // prefetch K for iter it+1
        ATTN_STEP(kA, vfA);

        short8 vfB[4];
        LOADV(vfB); vp += 2048;
        LOADK(kA);  kp += 2048;          // prefetch K for iter it+2; final pair over-reads
                                         // one tile past the slab end -- for b=7,h=7 that
                                         // is the start of Vf, still inside d_ws, unused.
        ATTN_STEP(kB, vfB);
    }

    float lp[4];
    #pragma unroll
    for (int qt = 0; qt < 4; ++qt) {
        lp[qt] = (lp4[qt][0] + lp4[qt][1]) + (lp4[qt][2] + lp4[qt][3]);
        lp[qt] += __shfl_xor(lp[qt], 16);
        lp[qt] += __shfl_xor(lp[qt], 32);
    }

    if (PARTIAL) {
        if (quad == 0) {
            #pragma unroll
            for (int qt = 0; qt < 4; ++qt)
                (Lbase + (size_t)h * 8 * SEQ)[(size_t)b * SEQ + s0 + 64 * w + 16 * qt + l15] = lp[qt];
        }
    } else {
        #pragma unroll
        for (int qt = 0; qt < 4; ++qt) {
            float inv[4];
            #pragma unroll
            for (int r = 0; r < 4; ++r) inv[r] = fast_rcp(__shfl(lp[qt], 4 * quad + r));
            #pragma unroll
            for (int ct = 0; ct < 4; ++ct)
                #pragma unroll
                for (int r = 0; r < 4; ++r) acc_o[qt][ct][r] *= inv[r];
        }
    }

    // ---- two-phase epilogue: wave ph's 64 rows through the 17.4KB sO buffer ----
    const int mws = tid & 15, cgs = tid >> 4;   // store mapping: 16 s-chunks x 8 chans
    #pragma unroll
    for (int ph = 0; ph < 2; ++ph) {
        __syncthreads();
        if (w == ph) {
            #pragma unroll
            for (int qt = 0; qt < 4; ++qt)
                #pragma unroll
                for (int ct = 0; ct < 4; ++ct) {
                    const int c = 16 * ct + l15;
                    #pragma unroll
                    for (int r = 0; r < 4; ++r)
                        sO[c * LDO + 16 * qt + 4 * quad + r] = acc_o[qt][ct][r];
                }
        }
        __syncthreads();
        const int sb = s0 + 64 * ph;
        if (PARTIAL) {
            unsigned short* Op = Obf + (size_t)h * 8 * DIM * SEQ;
            #pragma unroll
            for (int cc = 0; cc < 8; ++cc) {
                const int c = cgs + 8 * cc;
                const f32x4 v = *(const f32x4*)(sO + c * LDO + 4 * mws);
                *(ushort4*)(Op + ((size_t)b * DIM + c) * SEQ + sb + 4 * mws) =
                    make_ushort4(f2bf(v.x), f2bf(v.y), f2bf(v.z), f2bf(v.w));
            }
        } else {
            #pragma unroll
            for (int cc = 0; cc < 8; ++cc) {
                const int c = cgs + 8 * cc;
                const f32x4 v = *(const f32x4*)(sO + c * LDO + 4 * mws);
                *(f32x4*)(Out + ((size_t)b * DIM + c) * SEQ + sb + 4 * mws) = v;
            }
        }
    }
}

__global__ __launch_bounds__(256) void combine4(const unsigned short* __restrict__ Obf,
                                                const float* __restrict__ Lp,
                                                float* __restrict__ Out) {
    const int gid = blockIdx.x * 256 + threadIdx.x;
    const size_t base = (size_t)gid * 4;
    const int s = (int)(base & 4095);
    const int b = (int)(base >> 18);
    f32x4 os = (f32x4){0.f, 0.f, 0.f, 0.f};
    f32x4 ls = (f32x4){0.f, 0.f, 0.f, 0.f};
    #pragma unroll
    for (int h = 0; h < 8; ++h) {
        const ushort4 o = *(const ushort4*)(Obf + (size_t)h * 2097152 + base);
        os[0] += bf2f(o.x); os[1] += bf2f(o.y); os[2] += bf2f(o.z); os[3] += bf2f(o.w);
        const f32x4 l = *(const f32x4*)(Lp + (size_t)h * 8 * SEQ + b * SEQ + s);
        #pragma unroll
        for (int i = 0; i < 4; ++i) ls[i] += l[i];
    }
    f32x4 o;
    #pragma unroll
    for (int i = 0; i < 4; ++i) o[i] = os[i] / ls[i];
    *(f32x4*)(Out + base) = o;
}

__global__ __launch_bounds__(256, 2) void attn_fallback(const float* __restrict__ X,
                                                        float* __restrict__ Out) {
    __shared__ __align__(16) unsigned char smem[27648];
    unsigned short* sK = (unsigned short*)smem;
    unsigned short* sV = (unsigned short*)(smem + 9216);
    unsigned short* sP = (unsigned short*)(smem + 18432);
    float*          sO = (float*)smem;
    const int tid  = threadIdx.x;
    const int lane = tid & 63;
    const int w    = tid >> 6;
    const int l15  = lane & 15;
    const int quad = lane >> 4;
    const int b  = blockIdx.y;
    const int s0 = blockIdx.x * 64;
    const float* Xb = X + (size_t)b * DIM * SEQ;
    const int mgrp = tid & 15;
    const int c0   = tid >> 4;

    for (int cc = 0; cc < 4; ++cc) {
        int c = c0 + 16 * cc;
        const f32x4 v = *(const f32x4*)(Xb + (size_t)c * SEQ + s0 + 4 * mgrp);
        sK[(4 * mgrp + 0) * LDB + c] = f2bf(v.x);
        sK[(4 * mgrp + 1) * LDB + c] = f2bf(v.y);
        sK[(4 * mgrp + 2) * LDB + c] = f2bf(v.z);
        sK[(4 * mgrp + 3) * LDB + c] = f2bf(v.w);
    }
    __syncthreads();
    short8 qf0, qf1;
    {
        const int row = 16 * w + l15;
        qf0 = *(const short8*)(sK + row * LDB + quad * 8);
        qf1 = *(const short8*)(sK + row * LDB + 32 + quad * 8);
    }
    __syncthreads();
    f32x4 acc_o[4];
    for (int ct = 0; ct < 4; ++ct) acc_o[ct] = (f32x4){0.f, 0.f, 0.f, 0.f};
    float m_i[4] = {-1e30f, -1e30f, -1e30f, -1e30f};
    float l_i[4] = {0.f, 0.f, 0.f, 0.f};
    for (int kt = 0; kt < SEQ / 64; ++kt) {
        const int m0 = kt * 64;
        for (int cc = 0; cc < 4; ++cc) {
            int c = c0 + 16 * cc;
            const f32x4 v = *(const f32x4*)(Xb + (size_t)c * SEQ + m0 + 4 * mgrp);
            unsigned short h0 = f2bf(v.x), h1 = f2bf(v.y), h2 = f2bf(v.z), h3 = f2bf(v.w);
            *(ushort4*)(sV + c * LDB + 4 * mgrp) = make_ushort4(h0, h1, h2, h3);
            sK[(4 * mgrp + 0) * LDB + c] = h0;
            sK[(4 * mgrp + 1) * LDB + c] = h1;
            sK[(4 * mgrp + 2) * LDB + c] = h2;
            sK[(4 * mgrp + 3) * LDB + c] = h3;
        }
        __syncthreads();
        short8 vf[2][4];
        for (int ks = 0; ks < 2; ++ks)
            for (int ct = 0; ct < 4; ++ct)
                vf[ks][ct] = *(const short8*)(sV + (16 * ct + l15) * LDB + ks * 32 + quad * 8);
        f32x4 acc_s[4];
        for (int mt = 0; mt < 4; ++mt) {
            const int row = 16 * mt + l15;
            const short8 kf0 = *(const short8*)(sK + row * LDB + quad * 8);
            const short8 kf1 = *(const short8*)(sK + row * LDB + 32 + quad * 8);
            f32x4 a = (f32x4){0.f, 0.f, 0.f, 0.f};
            a = __builtin_amdgcn_mfma_f32_16x16x32_bf16(qf0, kf0, a, 0, 0, 0);
            a = __builtin_amdgcn_mfma_f32_16x16x32_bf16(qf1, kf1, a, 0, 0, 0);
            acc_s[mt] = a;
        }
        float alpha[4];
        for (int r = 0; r < 4; ++r) {
            float mx = fmaxf(fmaxf(acc_s[0][r], acc_s[1][r]), fmaxf(acc_s[2][r], acc_s[3][r]));
            mx = fmaxf(mx, __shfl_xor(mx, 1));
            mx = fmaxf(mx, __shfl_xor(mx, 2));
            mx = fmaxf(mx, __shfl_xor(mx, 4));
            mx = fmaxf(mx, __shfl_xor(mx, 8));
            const float mnew = fmaxf(m_i[r], mx);
            alpha[r] = __expf(m_i[r] - mnew);
            m_i[r] = mnew;
        }
        float rowsum[4] = {0.f, 0.f, 0.f, 0.f};
        unsigned short pb[4][4];
        for (int mt = 0; mt < 4; ++mt)
            for (int r = 0; r < 4; ++r) {
                const float p = __expf(acc_s[mt][r] - m_i[r]);
                rowsum[r] += p;
                pb[mt][r] = f2bf(p);
            }
        for (int r = 0; r < 4; ++r) {
            float s = rowsum[r];
            s += __shfl_xor(s, 1);
            s += __shfl_xor(s, 2);
            s += __shfl_xor(s, 4);
            s += __shfl_xor(s, 8);
            l_i[r] = alpha[r] * l_i[r] + s;
        }
        for (int ct = 0; ct < 4; ++ct)
            for (int r = 0; r < 4; ++r)
                acc_o[ct][r] *= alpha[r];
        for (int mt = 0; mt < 4; ++mt)
            for (int r = 0; r < 4; ++r)
                sP[(16 * w + quad * 4 + r) * LDB + l15 + 16 * mt] = pb[mt][r];
        __syncthreads();
        const short8 pf0 = *(const short8*)(sP + (16 * w + l15) * LDB + quad * 8);
        const short8 pf1 = *(const short8*)(sP + (16 * w + l15) * LDB + 32 + quad * 8);
        for (int ct = 0; ct < 4; ++ct) {
            acc_o[ct] = __builtin_amdgcn_mfma_f32_16x16x32_bf16(pf0, vf[0][ct], acc_o[ct], 0, 0, 0);
            acc_o[ct] = __builtin_amdgcn_mfma_f32_16x16x32_bf16(pf1, vf[1][ct], acc_o[ct], 0, 0, 0);
        }
    }
    float inv[4];
    for (int r = 0; r < 4; ++r) inv[r] = 1.f / l_i[r];
    for (int ct = 0; ct < 4; ++ct) {
        const int c = 16 * ct + l15;
        for (int r = 0; r < 4; ++r)
            sO[c * LDO + 16 * w + quad * 4 + r] = acc_o[ct][r] * inv[r];
    }
    __syncthreads();
    for (int cc = 0; cc < 4; ++cc) {
        const int c = c0 + 16 * cc;
        const f32x4 v = *(const f32x4*)(sO + c * LDO + 4 * mgrp);
        *(f32x4*)(Out + (size_t)b * DIM * SEQ + (size_t)c * SEQ + s0 + 4 * mgrp) = v;
    }
}

extern "C" void kernel_launch(void* const* d_in, const int* in_sizes, int n_in,
                              void* d_out, int out_size, void* d_ws, size_t ws_size,
                              hipStream_t stream) {
    const float* X = (const float*)d_in[0];
    float* Out = (float*)d_out;
    const size_t elems = (size_t)8 * SEQ * DIM;               // 2M
    const size_t offVf    = elems * 2;                        // Kf 4MB
    const size_t offNorms = offVf + elems * 2;                // Vf 4MB -> 8MB
    const size_t offMaxP  = offNorms + (size_t)8 * SEQ * 4;   // +128KB
    const size_t offObf   = offMaxP + 8 * 64 * 4;             // +2KB
    const size_t offLp    = offObf + 8 * elems * 2;           // +32MB (8 bf16 slabs)
    const size_t need     = offLp + 8 * (size_t)8 * SEQ * 4;  // +1MB  (~41.2MB total)

    if (ws_size >= need) {
        unsigned short* Kf = (unsigned short*)d_ws;
        unsigned short* Vf = (unsigned short*)((char*)d_ws + offVf);
        float* Norms   = (float*)((char*)d_ws + offNorms);
        float* MaxPart = (float*)((char*)d_ws + offMaxP);
        unsigned short* Obf = (unsigned short*)((char*)d_ws + offObf);
        float* Lp = (float*)((char*)d_ws + offLp);
        prepass4<<<dim3(64, 8), 256, 0, stream>>>(X, Kf, Vf, Norms, MaxPart);
        attn_split4<true><<<dim3(32, 8, 8), 128, 0, stream>>>(Kf, Vf, Norms, MaxPart,
                                                              Obf, Lp, nullptr, 16);
        combine4<<<(int)(elems / 1024), 256, 0, stream>>>(Obf, Lp, Out);
    } else {
        attn_fallback<<<dim3(64, 8), 256, 0, stream>>>(X, Out);
    }
}

// Round 11
// 119.620 us; speedup vs baseline: 3.0643x; 3.0643x over previous
//
#include <hip/hip_runtime.h>
#include <math.h>

// Non-local attention: X [8, 64, 64, 64] fp32.
// Per batch b: Q=K=V = X_b^T  [S=4096, D=64];  out = softmax(Q K^T) V, stored [b][c][s].
//
// R21: R20's split-K x8 experiment, re-run with the R13-proven register budget.
// R20's launch_bounds(128,3) was lowered to a VGPR cap of ~84 (512/6: the compiler
// composed min-waves-per-EU with the block's 2 waves), while this 64-rows/wave loop
// needs ~170 live VGPRs -> the accumulator spilled to scratch: VGPR_Count 84,
// FETCH/WRITE 397/664 MB (pure spill traffic), MfmaUtil 4.6%, 298us. The splitK8
// hypothesis was never tested. This round: identical kernel with launch_bounds(128,2)
// (the bound R13 ran at ~41us with this exact loop body). Expected ~160-190 VGPR,
// no spill, 3 waves/SIMD at the 2048-block grid.
// Structure (= R13 + splitK8): barrier-free LDS-free inner loop, per-wave global
// fragment loads (lane-contiguous 1KB per 16B-load), reg-double-buffered K, 64 Q
// rows/wave, zero-movement P (k-slot<->key bijection q*8+j <-> 16*(j>>2)+4q+(j&3)
// makes the PV A-frag the lane's own packed exp'd scores; Vf pre-permuted to match),
// XCD-pinned batch remap (b=gid&7), split-K x8 (niter 16), two-phase epilogue
// (17.4KB sO), combine over 8 partial slabs, C-S bound folded into the MFMA C-init.
//
// Kf[b][tile][mt][ks][lane]: scaled bf16, lane(=quad*16+l15) holds
//   XbfT_scaled[tile*32+mt*16+l15][quad*8+32*ks .. +8]   (also serves Q fragments)
// Vf[b][tile][ct][lane][j]: unscaled bf16, element j at lane (l15,q) holds
//   XbfT[tile*32 + 16*(j>>2) + 4*q + (j&3)][16*ct + l15]   (permuted B-frag order)

#define SEQ 4096
#define DIM 64
#define LDB 72
#define LDO 68
#define LDS2 68
#define QSCALE 1.2011224087864498f   // sqrt(log2(e))

typedef __attribute__((ext_vector_type(8))) short  short8;
typedef __attribute__((ext_vector_type(4))) float  f32x4;

__device__ __forceinline__ unsigned short f2bf(float f) {
    union { float f; unsigned int u; } x; x.f = f;
    unsigned int u = x.u + 0x7FFFu + ((x.u >> 16) & 1u);
    return (unsigned short)(u >> 16);
}
__device__ __forceinline__ float bf2f(unsigned short h) {
    union { unsigned int u; float f; } x; x.u = ((unsigned int)h) << 16; return x.f;
}
__device__ __forceinline__ float fast_exp2(float x) {
#if __has_builtin(__builtin_amdgcn_exp2f)
    return __builtin_amdgcn_exp2f(x);
#else
    float r;
    asm("v_exp_f32 %0, %1\n\ts_nop 0" : "=v"(r) : "v"(x));
    return r;
#endif
}
__device__ __forceinline__ float fast_rcp(float x) {
#if __has_builtin(__builtin_amdgcn_rcpf)
    return __builtin_amdgcn_rcpf(x);
#else
    return 1.f / x;
#endif
}

// ---------------- prepass: fragment-order bf16 arrays + scaled norms + max partials ----
__global__ __launch_bounds__(256) void prepass4(const float* __restrict__ X,
                                                unsigned short* __restrict__ Kf,
                                                unsigned short* __restrict__ Vf,
                                                float* __restrict__ Norms,
                                                float* __restrict__ MaxPart) {
    __shared__ __align__(16) unsigned short sT[64 * LDS2];    // scaled [m][c]
    __shared__ __align__(16) unsigned short sVu[64 * LDS2];   // unscaled [c][m]
    __shared__ float sRed[4];
    const int b = blockIdx.y, m0 = blockIdx.x * 64;
    const float* Xb = X + (size_t)b * DIM * SEQ;
    const int t = threadIdx.x, w = t >> 6;
    const int mw = t & 15, cg = t >> 4;

    #pragma unroll
    for (int cr = 0; cr < 4; ++cr) {
        const int c = cg * 4 + cr;
        const f32x4 v = *(const f32x4*)(Xb + (size_t)c * SEQ + m0 + 4 * mw);
        *(ushort4*)(sVu + c * LDS2 + 4 * mw) =
            make_ushort4(f2bf(v.x), f2bf(v.y), f2bf(v.z), f2bf(v.w));
        sT[(4 * mw + 0) * LDS2 + c] = f2bf(v.x * QSCALE);
        sT[(4 * mw + 1) * LDS2 + c] = f2bf(v.y * QSCALE);
        sT[(4 * mw + 2) * LDS2 + c] = f2bf(v.z * QSCALE);
        sT[(4 * mw + 3) * LDS2 + c] = f2bf(v.w * QSCALE);
    }
    __syncthreads();
    const int m = t >> 2, ck = t & 3;   // Kf mapping: key row m, dim-chunk pair ck

    // ---- Kf: row m, dim-chunks 2ck and 2ck+1 ----
    const short8 a0 = *(const short8*)(sT + m * LDS2 + ck * 16);
    const short8 a1 = *(const short8*)(sT + m * LDS2 + ck * 16 + 8);
    {
        const size_t base = (size_t)b * 262144 + (size_t)(m0 >> 5) * 2048;  // shorts
        #pragma unroll
        for (int j = 0; j < 2; ++j) {
            const int chunk = 2 * ck + j;
            const int tile = m >> 5, mt = (m >> 4) & 1;
            const int quad = chunk & 3, ks = chunk >> 2;
            const size_t off = base + (size_t)(tile * 4 + mt * 2 + ks) * 512
                                    + (size_t)(quad * 16 + (m & 15)) * 8;
            *(short8*)(Kf + off) = j ? a1 : a0;
        }
    }
    // ---- scaled row norm (from a0/a1), exact C-S bound on scaled scores ----
    float s = 0.f;
    #pragma unroll
    for (int i = 0; i < 8; ++i) {
        const float f0 = bf2f((unsigned short)a0[i]);
        const float f1 = bf2f((unsigned short)a1[i]);
        s += f0 * f0 + f1 * f1;
    }
    s += __shfl_xor(s, 1);
    s += __shfl_xor(s, 2);
    const float nm = sqrtf(s);
    if (ck == 0) Norms[(size_t)b * SEQ + m0 + m] = nm;

    // ---- Vf: permuted B-frag order, one contiguous 16B fragment per (tile,ct,lane) ----
    {
        const int ctv = (t >> 6) & 3, lv = t & 63;
        const int qv = lv >> 4, l15v = lv & 15;
        const int cidx = (16 * ctv + l15v) * LDS2;
        const size_t vbase = (size_t)b * 262144 + (size_t)(m0 >> 5) * 2048
                           + (size_t)ctv * 512 + (size_t)lv * 8;
        #pragma unroll
        for (int tl = 0; tl < 2; ++tl) {
            const ushort4 g0 = *(const ushort4*)(sVu + cidx + tl * 32 + 4 * qv);
            const ushort4 g1 = *(const ushort4*)(sVu + cidx + tl * 32 + 16 + 4 * qv);
            union { ushort4 g[2]; short8 v; } cat;
            cat.g[0] = g0; cat.g[1] = g1;
            *(short8*)(Vf + vbase + (size_t)tl * 2048) = cat.v;
        }
    }

    float mx = nm;
    #pragma unroll
    for (int d = 4; d < 64; d <<= 1) mx = fmaxf(mx, __shfl_xor(mx, d));
    if ((t & 63) == 0) sRed[w] = mx;
    __syncthreads();
    if (t == 0)
        MaxPart[b * 64 + blockIdx.x] =
            fmaxf(fmaxf(sRed[0], sRed[1]), fmaxf(sRed[2], sRed[3]));
}

// ---- per-iteration macros for the flash loop (kp/vp/qf/cin/acc_o/lp4 in scope) ----
#define LOADK(DST)                                                                 \
    {                                                                              \
        _Pragma("unroll")                                                          \
        for (int mt_ = 0; mt_ < 2; ++mt_) {                                        \
            _Pragma("unroll")                                                      \
            for (int ks_ = 0; ks_ < 2; ++ks_)                                      \
                DST[mt_][ks_] = *(const short8*)(kp + (mt_ * 2 + ks_) * 512);      \
        }                                                                          \
    }

#define LOADV(DST)                                                                 \
    {                                                                              \
        _Pragma("unroll")                                                          \
        for (int ct_ = 0; ct_ < 4; ++ct_)                                          \
            DST[ct_] = *(const short8*)(vp + ct_ * 512);                           \
    }

#define ATTN_STEP(KF, VF)                                                          \
    {                                                                              \
        f32x4 a_[4][2];                                                            \
        _Pragma("unroll")                                                          \
        for (int qt_ = 0; qt_ < 4; ++qt_) {                                        \
            _Pragma("unroll")                                                      \
            for (int mt_ = 0; mt_ < 2; ++mt_) {                                    \
                f32x4 s_ = cin[qt_];                                               \
                s_ = __builtin_amdgcn_mfma_f32_16x16x32_bf16(KF[mt_][0], qf[qt_][0], s_, 0, 0, 0); \
                s_ = __builtin_amdgcn_mfma_f32_16x16x32_bf16(KF[mt_][1], qf[qt_][1], s_, 0, 0, 0); \
                a_[qt_][mt_] = s_;                                                 \
            }                                                                      \
        }                                                                          \
        short8 pa_[4];                                                             \
        _Pragma("unroll")                                                          \
        for (int qt_ = 0; qt_ < 4; ++qt_) {                                        \
            union { unsigned u[4]; short8 v; } pk_;                                \
            _Pragma("unroll")                                                      \
            for (int mt_ = 0; mt_ < 2; ++mt_) {                                    \
                const float p0_ = fast_exp2(a_[qt_][mt_][0]);                      \
                const float p1_ = fast_exp2(a_[qt_][mt_][1]);                      \
                const float p2_ = fast_exp2(a_[qt_][mt_][2]);                      \
                const float p3_ = fast_exp2(a_[qt_][mt_][3]);                      \
                lp4[qt_] += (f32x4){p0_, p1_, p2_, p3_};                           \
                pk_.u[2 * mt_ + 0] = __builtin_amdgcn_perm(__float_as_uint(p1_), __float_as_uint(p0_), 0x07060302u); \
                pk_.u[2 * mt_ + 1] = __builtin_amdgcn_perm(__float_as_uint(p3_), __float_as_uint(p2_), 0x07060302u); \
            }                                                                      \
            pa_[qt_] = pk_.v;                                                      \
        }                                                                          \
        _Pragma("unroll")                                                          \
        for (int qt_ = 0; qt_ < 4; ++qt_) {                                        \
            _Pragma("unroll")                                                      \
            for (int ct_ = 0; ct_ < 4; ++ct_)                                      \
                acc_o[qt_][ct_] = __builtin_amdgcn_mfma_f32_16x16x32_bf16(pa_[qt_], VF[ct_], acc_o[qt_][ct_], 0, 0, 0); \
        }                                                                          \
    }

// Flash kernel: 2 waves x 64 Q rows, split-K x8, fragment-order global K/V,
// LDS-free inner loop (P feeds PV directly from registers at K=32).
template <bool PARTIAL>
__global__ __launch_bounds__(128, 2) void attn_split4(const unsigned short* __restrict__ Kf,
                                                      const unsigned short* __restrict__ Vf,
                                                      const float* __restrict__ Norms,
                                                      const float* __restrict__ MaxPart,
                                                      unsigned short* __restrict__ Obf,  // PARTIAL
                                                      float* __restrict__ Lbase,         // PARTIAL
                                                      float* __restrict__ Out,           // !PARTIAL
                                                      int niter) {
    __shared__ __align__(16) float sO[64 * LDO];   // two-phase epilogue buffer (17408 B)

    const int tid  = threadIdx.x;
    const int lane = tid & 63;
    const int w    = tid >> 6;
    const int l15  = lane & 15;
    const int quad = lane >> 4;

    // XCD-pinned work remap: dispatch round-robins linear wg id across the 8 XCDs,
    // so gid&7 == XCD. Assign batch = gid&7 so each XCD streams exactly one batch's
    // slabs (L2-resident). Pure work remap -- placement only affects speed.
    const int gid  = blockIdx.x + 32 * (blockIdx.y + 8 * blockIdx.z);
    const int b    = gid & 7;
    const int rest = gid >> 3;             // 0..255
    const int s0   = (rest & 31) * 128;    // 128 Q rows per block
    const int h    = rest >> 5;            // 0..7 split-K eighth
    const int kt0  = h * niter;
    const unsigned short* Kfb = Kf + (size_t)b * 262144;
    const unsigned short* Vfb = Vf + (size_t)b * 262144;

    float mxn = MaxPart[b * 64 + lane];
    #pragma unroll
    for (int d = 1; d < 64; d <<= 1) mxn = fmaxf(mxn, __shfl_xor(mxn, d));

    // Q frags from Kf (scaled): wave w owns rows s0+64w .. +63 (qt = 0..3)
    short8 qf[4][2];
    f32x4 cin[4];
    const int qtile = (s0 + 64 * w) >> 5;
    #pragma unroll
    for (int qt = 0; qt < 4; ++qt) {
        #pragma unroll
        for (int ks = 0; ks < 2; ++ks)
            qf[qt][ks] = *(const short8*)(Kfb
                + (size_t)((qtile + (qt >> 1)) * 4 + (qt & 1) * 2 + ks) * 512 + lane * 8);
        const float mrow = Norms[(size_t)b * SEQ + s0 + 64 * w + 16 * qt + l15] * mxn;
        cin[qt] = (f32x4){-mrow, -mrow, -mrow, -mrow};
    }

    f32x4 acc_o[4][4];
    #pragma unroll
    for (int qt = 0; qt < 4; ++qt)
        #pragma unroll
        for (int ct = 0; ct < 4; ++ct) acc_o[qt][ct] = (f32x4){0.f, 0.f, 0.f, 0.f};
    f32x4 lp4[4];
    #pragma unroll
    for (int qt = 0; qt < 4; ++qt) lp4[qt] = (f32x4){0.f, 0.f, 0.f, 0.f};

    // ---- fragment stream pointers (lane-contiguous 1KB per 16B-load) ----
    const unsigned short* kp = Kfb + (size_t)kt0 * 2048 + lane * 8;
    const unsigned short* vp = Vfb + (size_t)kt0 * 2048 + lane * 8;

    short8 kA[2][2], kB[2][2];
    LOADK(kA);
    kp += 2048;

    for (int it = 0; it < niter; it += 2) {
        short8 vfA[4];
        LOADV(vfA); vp += 2048;
        LOADK(kB);  kp += 2048;          // prefetch K for iter it+1
        ATTN_STEP(kA, vfA);

        short8 vfB[4];
        LOADV(vfB); vp += 2048;
        LOADK(kA);  kp += 2048;          // prefetch K for iter it+2; final pair over-reads
                                         // one tile past the slab end -- for b=7,h=7 that
                                         // is the start of Vf, still inside d_ws, unused.
        ATTN_STEP(kB, vfB);
    }

    float lp[4];
    #pragma unroll
    for (int qt = 0; qt < 4; ++qt) {
        lp[qt] = (lp4[qt][0] + lp4[qt][1]) + (lp4[qt][2] + lp4[qt][3]);
        lp[qt] += __shfl_xor(lp[qt], 16);
        lp[qt] += __shfl_xor(lp[qt], 32);
    }

    if (PARTIAL) {
        if (quad == 0) {
            #pragma unroll
            for (int qt = 0; qt < 4; ++qt)
                (Lbase + (size_t)h * 8 * SEQ)[(size_t)b * SEQ + s0 + 64 * w + 16 * qt + l15] = lp[qt];
        }
    } else {
        #pragma unroll
        for (int qt = 0; qt < 4; ++qt) {
            float inv[4];
            #pragma unroll
            for (int r = 0; r < 4; ++r) inv[r] = fast_rcp(__shfl(lp[qt], 4 * quad + r));
            #pragma unroll
            for (int ct = 0; ct < 4; ++ct)
                #pragma unroll
                for (int r = 0; r < 4; ++r) acc_o[qt][ct][r] *= inv[r];
        }
    }

    // ---- two-phase epilogue: wave ph's 64 rows through the 17.4KB sO buffer ----
    const int mws = tid & 15, cgs = tid >> 4;   // store mapping: 16 s-chunks x 8 chans
    #pragma unroll
    for (int ph = 0; ph < 2; ++ph) {
        __syncthreads();
        if (w == ph) {
            #pragma unroll
            for (int qt = 0; qt < 4; ++qt)
                #pragma unroll
                for (int ct = 0; ct < 4; ++ct) {
                    const int c = 16 * ct + l15;
                    #pragma unroll
                    for (int r = 0; r < 4; ++r)
                        sO[c * LDO + 16 * qt + 4 * quad + r] = acc_o[qt][ct][r];
                }
        }
        __syncthreads();
        const int sb = s0 + 64 * ph;
        if (PARTIAL) {
            unsigned short* Op = Obf + (size_t)h * 8 * DIM * SEQ;
            #pragma unroll
            for (int cc = 0; cc < 8; ++cc) {
                const int c = cgs + 8 * cc;
                const f32x4 v = *(const f32x4*)(sO + c * LDO + 4 * mws);
                *(ushort4*)(Op + ((size_t)b * DIM + c) * SEQ + sb + 4 * mws) =
                    make_ushort4(f2bf(v.x), f2bf(v.y), f2bf(v.z), f2bf(v.w));
            }
        } else {
            #pragma unroll
            for (int cc = 0; cc < 8; ++cc) {
                const int c = cgs + 8 * cc;
                const f32x4 v = *(const f32x4*)(sO + c * LDO + 4 * mws);
                *(f32x4*)(Out + ((size_t)b * DIM + c) * SEQ + sb + 4 * mws) = v;
            }
        }
    }
}

__global__ __launch_bounds__(256) void combine4(const unsigned short* __restrict__ Obf,
                                                const float* __restrict__ Lp,
                                                float* __restrict__ Out) {
    const int gid = blockIdx.x * 256 + threadIdx.x;
    const size_t base = (size_t)gid * 4;
    const int s = (int)(base & 4095);
    const int b = (int)(base >> 18);
    f32x4 os = (f32x4){0.f, 0.f, 0.f, 0.f};
    f32x4 ls = (f32x4){0.f, 0.f, 0.f, 0.f};
    #pragma unroll
    for (int h = 0; h < 8; ++h) {
        const ushort4 o = *(const ushort4*)(Obf + (size_t)h * 2097152 + base);
        os[0] += bf2f(o.x); os[1] += bf2f(o.y); os[2] += bf2f(o.z); os[3] += bf2f(o.w);
        const f32x4 l = *(const f32x4*)(Lp + (size_t)h * 8 * SEQ + b * SEQ + s);
        #pragma unroll
        for (int i = 0; i < 4; ++i) ls[i] += l[i];
    }
    f32x4 o;
    #pragma unroll
    for (int i = 0; i < 4; ++i) o[i] = os[i] / ls[i];
    *(f32x4*)(Out + base) = o;
}

__global__ __launch_bounds__(256, 2) void attn_fallback(const float* __restrict__ X,
                                                        float* __restrict__ Out) {
    __shared__ __align__(16) unsigned char smem[27648];
    unsigned short* sK = (unsigned short*)smem;
    unsigned short* sV = (unsigned short*)(smem + 9216);
    unsigned short* sP = (unsigned short*)(smem + 18432);
    float*          sO = (float*)smem;
    const int tid  = threadIdx.x;
    const int lane = tid & 63;
    const int w    = tid >> 6;
    const int l15  = lane & 15;
    const int quad = lane >> 4;
    const int b  = blockIdx.y;
    const int s0 = blockIdx.x * 64;
    const float* Xb = X + (size_t)b * DIM * SEQ;
    const int mgrp = tid & 15;
    const int c0   = tid >> 4;

    for (int cc = 0; cc < 4; ++cc) {
        int c = c0 + 16 * cc;
        const f32x4 v = *(const f32x4*)(Xb + (size_t)c * SEQ + s0 + 4 * mgrp);
        sK[(4 * mgrp + 0) * LDB + c] = f2bf(v.x);
        sK[(4 * mgrp + 1) * LDB + c] = f2bf(v.y);
        sK[(4 * mgrp + 2) * LDB + c] = f2bf(v.z);
        sK[(4 * mgrp + 3) * LDB + c] = f2bf(v.w);
    }
    __syncthreads();
    short8 qf0, qf1;
    {
        const int row = 16 * w + l15;
        qf0 = *(const short8*)(sK + row * LDB + quad * 8);
        qf1 = *(const short8*)(sK + row * LDB + 32 + quad * 8);
    }
    __syncthreads();
    f32x4 acc_o[4];
    for (int ct = 0; ct < 4; ++ct) acc_o[ct] = (f32x4){0.f, 0.f, 0.f, 0.f};
    float m_i[4] = {-1e30f, -1e30f, -1e30f, -1e30f};
    float l_i[4] = {0.f, 0.f, 0.f, 0.f};
    for (int kt = 0; kt < SEQ / 64; ++kt) {
        const int m0 = kt * 64;
        for (int cc = 0; cc < 4; ++cc) {
            int c = c0 + 16 * cc;
            const f32x4 v = *(const f32x4*)(Xb + (size_t)c * SEQ + m0 + 4 * mgrp);
            unsigned short h0 = f2bf(v.x), h1 = f2bf(v.y), h2 = f2bf(v.z), h3 = f2bf(v.w);
            *(ushort4*)(sV + c * LDB + 4 * mgrp) = make_ushort4(h0, h1, h2, h3);
            sK[(4 * mgrp + 0) * LDB + c] = h0;
            sK[(4 * mgrp + 1) * LDB + c] = h1;
            sK[(4 * mgrp + 2) * LDB + c] = h2;
            sK[(4 * mgrp + 3) * LDB + c] = h3;
        }
        __syncthreads();
        short8 vf[2][4];
        for (int ks = 0; ks < 2; ++ks)
            for (int ct = 0; ct < 4; ++ct)
                vf[ks][ct] = *(const short8*)(sV + (16 * ct + l15) * LDB + ks * 32 + quad * 8);
        f32x4 acc_s[4];
        for (int mt = 0; mt < 4; ++mt) {
            const int row = 16 * mt + l15;
            const short8 kf0 = *(const short8*)(sK + row * LDB + quad * 8);
            const short8 kf1 = *(const short8*)(sK + row * LDB + 32 + quad * 8);
            f32x4 a = (f32x4){0.f, 0.f, 0.f, 0.f};
            a = __builtin_amdgcn_mfma_f32_16x16x32_bf16(qf0, kf0, a, 0, 0, 0);
            a = __builtin_amdgcn_mfma_f32_16x16x32_bf16(qf1, kf1, a, 0, 0, 0);
            acc_s[mt] = a;
        }
        float alpha[4];
        for (int r = 0; r < 4; ++r) {
            float mx = fmaxf(fmaxf(acc_s[0][r], acc_s[1][r]), fmaxf(acc_s[2][r], acc_s[3][r]));
            mx = fmaxf(mx, __shfl_xor(mx, 1));
            mx = fmaxf(mx, __shfl_xor(mx, 2));
            mx = fmaxf(mx, __shfl_xor(mx, 4));
            mx = fmaxf(mx, __shfl_xor(mx, 8));
            const float mnew = fmaxf(m_i[r], mx);
            alpha[r] = __expf(m_i[r] - mnew);
            m_i[r] = mnew;
        }
        float rowsum[4] = {0.f, 0.f, 0.f, 0.f};
        unsigned short pb[4][4];
        for (int mt = 0; mt < 4; ++mt)
            for (int r = 0; r < 4; ++r) {
                const float p = __expf(acc_s[mt][r] - m_i[r]);
                rowsum[r] += p;
                pb[mt][r] = f2bf(p);
            }
        for (int r = 0; r < 4; ++r) {
            float s = rowsum[r];
            s += __shfl_xor(s, 1);
            s += __shfl_xor(s, 2);
            s += __shfl_xor(s, 4);
            s += __shfl_xor(s, 8);
            l_i[r] = alpha[r] * l_i[r] + s;
        }
        for (int ct = 0; ct < 4; ++ct)
            for (int r = 0; r < 4; ++r)
                acc_o[ct][r] *= alpha[r];
        for (int mt = 0; mt < 4; ++mt)
            for (int r = 0; r < 4; ++r)
                sP[(16 * w + quad * 4 + r) * LDB + l15 + 16 * mt] = pb[mt][r];
        __syncthreads();
        const short8 pf0 = *(const short8*)(sP + (16 * w + l15) * LDB + quad * 8);
        const short8 pf1 = *(const short8*)(sP + (16 * w + l15) * LDB + 32 + quad * 8);
        for (int ct = 0; ct < 4; ++ct) {
            acc_o[ct] = __builtin_amdgcn_mfma_f32_16x16x32_bf16(pf0, vf[0][ct], acc_o[ct], 0, 0, 0);
            acc_o[ct] = __builtin_amdgcn_mfma_f32_16x16x32_bf16(pf1, vf[1][ct], acc_o[ct], 0, 0, 0);
        }
    }
    float inv[4];
    for (int r = 0; r < 4; ++r) inv[r] = 1.f / l_i[r];
    for (int ct = 0; ct < 4; ++ct) {
        const int c = 16 * ct + l15;
        for (int r = 0; r < 4; ++r)
            sO[c * LDO + 16 * w + quad * 4 + r] = acc_o[ct][r] * inv[r];
    }
    __syncthreads();
    for (int cc = 0; cc < 4; ++cc) {
        const int c = c0 + 16 * cc;
        const f32x4 v = *(const f32x4*)(sO + c * LDO + 4 * mgrp);
        *(f32x4*)(Out + (size_t)b * DIM * SEQ + (size_t)c * SEQ + s0 + 4 * mgrp) = v;
    }
}

extern "C" void kernel_launch(void* const* d_in, const int* in_sizes, int n_in,
                              void* d_out, int out_size, void* d_ws, size_t ws_size,
                              hipStream_t stream) {
    const float* X = (const float*)d_in[0];
    float* Out = (float*)d_out;
    const size_t elems = (size_t)8 * SEQ * DIM;               // 2M
    const size_t offVf    = elems * 2;                        // Kf 4MB
    const size_t offNorms = offVf + elems * 2;                // Vf 4MB -> 8MB
    const size_t offMaxP  = offNorms + (size_t)8 * SEQ * 4;   // +128KB
    const size_t offObf   = offMaxP + 8 * 64 * 4;             // +2KB
    const size_t offLp    = offObf + 8 * elems * 2;           // +32MB (8 bf16 slabs)
    const size_t need     = offLp + 8 * (size_t)8 * SEQ * 4;  // +1MB  (~41.2MB total)

    if (ws_size >= need) {
        unsigned short* Kf = (unsigned short*)d_ws;
        unsigned short* Vf = (unsigned short*)((char*)d_ws + offVf);
        float* Norms   = (float*)((char*)d_ws + offNorms);
        float* MaxPart = (float*)((char*)d_ws + offMaxP);
        unsigned short* Obf = (unsigned short*)((char*)d_ws + offObf);
        float* Lp = (float*)((char*)d_ws + offLp);
        prepass4<<<dim3(64, 8), 256, 0, stream>>>(X, Kf, Vf, Norms, MaxPart);
        attn_split4<true><<<dim3(32, 8, 8), 128, 0, stream>>>(Kf, Vf, Norms, MaxPart,
                                                              Obf, Lp, nullptr, 16);
        combine4<<<(int)(elems / 1024), 256, 0, stream>>>(Obf, Lp, Out);
    } else {
        attn_fallback<<<dim3(64, 8), 256, 0, stream>>>(X, Out);
    }
}

// Round 13
// 106.949 us; speedup vs baseline: 3.4274x; 1.1185x over previous
//
#include <hip/hip_runtime.h>
#include <math.h>

// Non-local attention: X [8, 64, 64, 64] fp32.
// Per batch b: Q=K=V = X_b^T  [S=4096, D=64];  out = softmax(Q K^T) V, stored [b][c][s].
//
// R23 (= R22 resubmit after infra failure): R13 (proven best, 105.7us total) +
// deep V-prefetch. The 11-round matrix showed duration invariant to waves/SIMD
// (2->4), MFMA count (/2), staged bytes (/4), split depth (x2) -- but per-wave
// load concurrency (8 loads in flight) was never varied. This round: flash loop
// unrolled by 4, ALL four V-tile loads + the next K hoisted to the super-block top
// (20 loads / 20KB in flight), K rotated through the kA/kB double buffer mid-stream
// (each LOADK lands after its buffer's STEP consumed it). asm memory fence pins the
// hoisted loads against sinking.
// OOB audit: final super-block's last LOADK reads tile kt0+32; worst case (b=7,h=3)
// = start of Vf, inside d_ws, values unused. V stream stays within the h-slice.
// Everything else byte-identical to R13: barrier-free LDS-free inner loop, 64 Q
// rows/wave, zero-movement P (k-slot<->key bijection q*8+j <-> 16*(j>>2)+4q+(j&3)
// makes the PV A-frag the lane's own packed exp'd scores; Vf pre-permuted), XCD-
// pinned batch remap (b=gid&7), split-K x4 (niter 32), single-phase 34KB epilogue,
// combine over 4 slabs, C-S bound folded into the MFMA C-init, launch_bounds(128,2).
//
// Kf[b][tile][mt][ks][lane]: scaled bf16, lane(=quad*16+l15) holds
//   XbfT_scaled[tile*32+mt*16+l15][quad*8+32*ks .. +8]   (also serves Q fragments)
// Vf[b][tile][ct][lane][j]: unscaled bf16, element j at lane (l15,q) holds
//   XbfT[tile*32 + 16*(j>>2) + 4*q + (j&3)][16*ct + l15]   (permuted B-frag order)

#define SEQ 4096
#define DIM 64
#define LDB 72
#define LDO 68
#define LDO2 133
#define LDS2 68
#define QSCALE 1.2011224087864498f   // sqrt(log2(e))

typedef __attribute__((ext_vector_type(8))) short  short8;
typedef __attribute__((ext_vector_type(4))) float  f32x4;

__device__ __forceinline__ unsigned short f2bf(float f) {
    union { float f; unsigned int u; } x; x.f = f;
    unsigned int u = x.u + 0x7FFFu + ((x.u >> 16) & 1u);
    return (unsigned short)(u >> 16);
}
__device__ __forceinline__ float bf2f(unsigned short h) {
    union { unsigned int u; float f; } x; x.u = ((unsigned int)h) << 16; return x.f;
}
__device__ __forceinline__ float fast_exp2(float x) {
#if __has_builtin(__builtin_amdgcn_exp2f)
    return __builtin_amdgcn_exp2f(x);
#else
    float r;
    asm("v_exp_f32 %0, %1\n\ts_nop 0" : "=v"(r) : "v"(x));
    return r;
#endif
}
__device__ __forceinline__ float fast_rcp(float x) {
#if __has_builtin(__builtin_amdgcn_rcpf)
    return __builtin_amdgcn_rcpf(x);
#else
    return 1.f / x;
#endif
}

// ---------------- prepass: fragment-order bf16 arrays + scaled norms + max partials ----
__global__ __launch_bounds__(256) void prepass4(const float* __restrict__ X,
                                                unsigned short* __restrict__ Kf,
                                                unsigned short* __restrict__ Vf,
                                                float* __restrict__ Norms,
                                                float* __restrict__ MaxPart) {
    __shared__ __align__(16) unsigned short sT[64 * LDS2];    // scaled [m][c]
    __shared__ __align__(16) unsigned short sVu[64 * LDS2];   // unscaled [c][m]
    __shared__ float sRed[4];
    const int b = blockIdx.y, m0 = blockIdx.x * 64;
    const float* Xb = X + (size_t)b * DIM * SEQ;
    const int t = threadIdx.x, w = t >> 6;
    const int mw = t & 15, cg = t >> 4;

    #pragma unroll
    for (int cr = 0; cr < 4; ++cr) {
        const int c = cg * 4 + cr;
        const f32x4 v = *(const f32x4*)(Xb + (size_t)c * SEQ + m0 + 4 * mw);
        *(ushort4*)(sVu + c * LDS2 + 4 * mw) =
            make_ushort4(f2bf(v.x), f2bf(v.y), f2bf(v.z), f2bf(v.w));
        sT[(4 * mw + 0) * LDS2 + c] = f2bf(v.x * QSCALE);
        sT[(4 * mw + 1) * LDS2 + c] = f2bf(v.y * QSCALE);
        sT[(4 * mw + 2) * LDS2 + c] = f2bf(v.z * QSCALE);
        sT[(4 * mw + 3) * LDS2 + c] = f2bf(v.w * QSCALE);
    }
    __syncthreads();
    const int m = t >> 2, ck = t & 3;   // Kf mapping: key row m, dim-chunk pair ck

    // ---- Kf: row m, dim-chunks 2ck and 2ck+1 ----
    const short8 a0 = *(const short8*)(sT + m * LDS2 + ck * 16);
    const short8 a1 = *(const short8*)(sT + m * LDS2 + ck * 16 + 8);
    {
        const size_t base = (size_t)b * 262144 + (size_t)(m0 >> 5) * 2048;  // shorts
        #pragma unroll
        for (int j = 0; j < 2; ++j) {
            const int chunk = 2 * ck + j;
            const int tile = m >> 5, mt = (m >> 4) & 1;
            const int quad = chunk & 3, ks = chunk >> 2;
            const size_t off = base + (size_t)(tile * 4 + mt * 2 + ks) * 512
                                    + (size_t)(quad * 16 + (m & 15)) * 8;
            *(short8*)(Kf + off) = j ? a1 : a0;
        }
    }
    // ---- scaled row norm (from a0/a1), exact C-S bound on scaled scores ----
    float s = 0.f;
    #pragma unroll
    for (int i = 0; i < 8; ++i) {
        const float f0 = bf2f((unsigned short)a0[i]);
        const float f1 = bf2f((unsigned short)a1[i]);
        s += f0 * f0 + f1 * f1;
    }
    s += __shfl_xor(s, 1);
    s += __shfl_xor(s, 2);
    const float nm = sqrtf(s);
    if (ck == 0) Norms[(size_t)b * SEQ + m0 + m] = nm;

    // ---- Vf: permuted B-frag order, one contiguous 16B fragment per (tile,ct,lane) ----
    {
        const int ctv = (t >> 6) & 3, lv = t & 63;
        const int qv = lv >> 4, l15v = lv & 15;
        const int cidx = (16 * ctv + l15v) * LDS2;
        const size_t vbase = (size_t)b * 262144 + (size_t)(m0 >> 5) * 2048
                           + (size_t)ctv * 512 + (size_t)lv * 8;
        #pragma unroll
        for (int tl = 0; tl < 2; ++tl) {
            const ushort4 g0 = *(const ushort4*)(sVu + cidx + tl * 32 + 4 * qv);
            const ushort4 g1 = *(const ushort4*)(sVu + cidx + tl * 32 + 16 + 4 * qv);
            union { ushort4 g[2]; short8 v; } cat;
            cat.g[0] = g0; cat.g[1] = g1;
            *(short8*)(Vf + vbase + (size_t)tl * 2048) = cat.v;
        }
    }

    float mx = nm;
    #pragma unroll
    for (int d = 4; d < 64; d <<= 1) mx = fmaxf(mx, __shfl_xor(mx, d));
    if ((t & 63) == 0) sRed[w] = mx;
    __syncthreads();
    if (t == 0)
        MaxPart[b * 64 + blockIdx.x] =
            fmaxf(fmaxf(sRed[0], sRed[1]), fmaxf(sRed[2], sRed[3]));
}

// ---- per-iteration macros for the flash loop (kp/vp/qf/cin/acc_o/lp4 in scope) ----
#define LOADK(DST)                                                                 \
    {                                                                              \
        _Pragma("unroll")                                                          \
        for (int mt_ = 0; mt_ < 2; ++mt_) {                                        \
            _Pragma("unroll")                                                      \
            for (int ks_ = 0; ks_ < 2; ++ks_)                                      \
                DST[mt_][ks_] = *(const short8*)(kp + (mt_ * 2 + ks_) * 512);      \
        }                                                                          \
    }

#define LOADV(DST)                                                                 \
    {                                                                              \
        _Pragma("unroll")                                                          \
        for (int ct_ = 0; ct_ < 4; ++ct_)                                          \
            DST[ct_] = *(const short8*)(vp + ct_ * 512);                           \
    }

#define ATTN_STEP(KF, VF)                                                          \
    {                                                                              \
        f32x4 a_[4][2];                                                            \
        _Pragma("unroll")                                                          \
        for (int qt_ = 0; qt_ < 4; ++qt_) {                                        \
            _Pragma("unroll")                                                      \
            for (int mt_ = 0; mt_ < 2; ++mt_) {                                    \
                f32x4 s_ = cin[qt_];                                               \
                s_ = __builtin_amdgcn_mfma_f32_16x16x32_bf16(KF[mt_][0], qf[qt_][0], s_, 0, 0, 0); \
                s_ = __builtin_amdgcn_mfma_f32_16x16x32_bf16(KF[mt_][1], qf[qt_][1], s_, 0, 0, 0); \
                a_[qt_][mt_] = s_;                                                 \
            }                                                                      \
        }                                                                          \
        short8 pa_[4];                                                             \
        _Pragma("unroll")                                                          \
        for (int qt_ = 0; qt_ < 4; ++qt_) {                                        \
            union { unsigned u[4]; short8 v; } pk_;                                \
            _Pragma("unroll")                                                      \
            for (int mt_ = 0; mt_ < 2; ++mt_) {                                    \
                const float p0_ = fast_exp2(a_[qt_][mt_][0]);                      \
                const float p1_ = fast_exp2(a_[qt_][mt_][1]);                      \
                const float p2_ = fast_exp2(a_[qt_][mt_][2]);                      \
                const float p3_ = fast_exp2(a_[qt_][mt_][3]);                      \
                lp4[qt_] += (f32x4){p0_, p1_, p2_, p3_};                           \
                pk_.u[2 * mt_ + 0] = __builtin_amdgcn_perm(__float_as_uint(p1_), __float_as_uint(p0_), 0x07060302u); \
                pk_.u[2 * mt_ + 1] = __builtin_amdgcn_perm(__float_as_uint(p3_), __float_as_uint(p2_), 0x07060302u); \
            }                                                                      \
            pa_[qt_] = pk_.v;                                                      \
        }                                                                          \
        _Pragma("unroll")                                                          \
        for (int qt_ = 0; qt_ < 4; ++qt_) {                                        \
            _Pragma("unroll")                                                      \
            for (int ct_ = 0; ct_ < 4; ++ct_)                                      \
                acc_o[qt_][ct_] = __builtin_amdgcn_mfma_f32_16x16x32_bf16(pa_[qt_], VF[ct_], acc_o[qt_][ct_], 0, 0, 0); \
        }                                                                          \
    }

// Flash kernel: 2 waves x 64 Q rows, split-K x4. Fragment-order global K/V,
// LDS-free inner loop (P feeds PV directly from registers at K=32).
// R23: 4-iter super-block with all V loads + next-K hoisted (20 loads in flight).
template <bool PARTIAL>
__global__ __launch_bounds__(128, 2) void attn_split4(const unsigned short* __restrict__ Kf,
                                                      const unsigned short* __restrict__ Vf,
                                                      const float* __restrict__ Norms,
                                                      const float* __restrict__ MaxPart,
                                                      unsigned short* __restrict__ Obf,  // PARTIAL
                                                      float* __restrict__ Lbase,         // PARTIAL
                                                      float* __restrict__ Out,           // !PARTIAL
                                                      int niter) {
    __shared__ __align__(16) float sO[64 * LDO2];   // epilogue staging only (34048 B)

    const int tid  = threadIdx.x;
    const int lane = tid & 63;
    const int w    = tid >> 6;
    const int l15  = lane & 15;
    const int quad = lane >> 4;

    // XCD-pinned work remap: dispatch round-robins linear wg id across the 8 XCDs,
    // so gid&7 == XCD. Assign batch = gid&7 so each XCD streams exactly one batch's
    // 1MB K/V slab (L2-resident). Pure work remap -- placement only affects speed.
    const int gid  = blockIdx.x + 32 * (blockIdx.y + 8 * blockIdx.z);
    const int b    = gid & 7;
    const int rest = gid >> 3;             // 0..127
    const int s0   = (rest & 31) * 128;    // 128 Q rows per block
    const int h    = rest >> 5;            // 0..3 split-K quarter
    const int kt0  = h * niter;
    const unsigned short* Kfb = Kf + (size_t)b * 262144;
    const unsigned short* Vfb = Vf + (size_t)b * 262144;

    float mxn = MaxPart[b * 64 + lane];
    #pragma unroll
    for (int d = 1; d < 64; d <<= 1) mxn = fmaxf(mxn, __shfl_xor(mxn, d));

    // Q frags from Kf (scaled): wave w owns rows s0+64w .. +63 (qt = 0..3)
    short8 qf[4][2];
    f32x4 cin[4];
    const int qtile = (s0 + 64 * w) >> 5;
    #pragma unroll
    for (int qt = 0; qt < 4; ++qt) {
        #pragma unroll
        for (int ks = 0; ks < 2; ++ks)
            qf[qt][ks] = *(const short8*)(Kfb
                + (size_t)((qtile + (qt >> 1)) * 4 + (qt & 1) * 2 + ks) * 512 + lane * 8);
        const float mrow = Norms[(size_t)b * SEQ + s0 + 64 * w + 16 * qt + l15] * mxn;
        cin[qt] = (f32x4){-mrow, -mrow, -mrow, -mrow};
    }

    f32x4 acc_o[4][4];
    #pragma unroll
    for (int qt = 0; qt < 4; ++qt)
        #pragma unroll
        for (int ct = 0; ct < 4; ++ct) acc_o[qt][ct] = (f32x4){0.f, 0.f, 0.f, 0.f};
    f32x4 lp4[4];
    #pragma unroll
    for (int qt = 0; qt < 4; ++qt) lp4[qt] = (f32x4){0.f, 0.f, 0.f, 0.f};

    // ---- fragment stream pointers (lane-contiguous 1KB per 16B-load) ----
    const unsigned short* kp = Kfb + (size_t)kt0 * 2048 + lane * 8;
    const unsigned short* vp = Vfb + (size_t)kt0 * 2048 + lane * 8;

    short8 kA[2][2], kB[2][2];
    LOADK(kA);                         // tile kt0
    kp += 2048;

    for (int it = 0; it < niter; it += 4) {
        // ---- super-block top: all 4 V tiles + next K issued (20 loads in flight) ----
        short8 vf0[4], vf1[4], vf2[4], vf3[4];
        LOADV(vf0); vp += 2048;
        LOADK(kB);  kp += 2048;        // tile it+1
        LOADV(vf1); vp += 2048;
        LOADV(vf2); vp += 2048;
        LOADV(vf3); vp += 2048;
        asm volatile("" ::: "memory"); // pin hoisted loads above the compute
        ATTN_STEP(kA, vf0);
        LOADK(kA);  kp += 2048;        // tile it+2 (kA consumed by STEP above)
        ATTN_STEP(kB, vf1);
        LOADK(kB);  kp += 2048;        // tile it+3
        ATTN_STEP(kA, vf2);
        LOADK(kA);  kp += 2048;        // tile it+4; on the final super-block this
                                       // over-reads one tile past the h-slice --
                                       // still inside d_ws (Kf/Vf slabs), unused.
        ATTN_STEP(kB, vf3);
    }

    float lp[4];
    #pragma unroll
    for (int qt = 0; qt < 4; ++qt) {
        lp[qt] = (lp4[qt][0] + lp4[qt][1]) + (lp4[qt][2] + lp4[qt][3]);
        lp[qt] += __shfl_xor(lp[qt], 16);
        lp[qt] += __shfl_xor(lp[qt], 32);
    }

    if (PARTIAL) {
        if (quad == 0) {
            #pragma unroll
            for (int qt = 0; qt < 4; ++qt)
                (Lbase + (size_t)h * 8 * SEQ)[(size_t)b * SEQ + s0 + 64 * w + 16 * qt + l15] = lp[qt];
        }
    } else {
        #pragma unroll
        for (int qt = 0; qt < 4; ++qt) {
            float inv[4];
            #pragma unroll
            for (int r = 0; r < 4; ++r) inv[r] = fast_rcp(__shfl(lp[qt], 4 * quad + r));
            #pragma unroll
            for (int ct = 0; ct < 4; ++ct)
                #pragma unroll
                for (int r = 0; r < 4; ++r) acc_o[qt][ct][r] *= inv[r];
        }
    }

    #pragma unroll
    for (int qt = 0; qt < 4; ++qt)
        #pragma unroll
        for (int ct = 0; ct < 4; ++ct) {
            const int c = 16 * ct + l15;
            #pragma unroll
            for (int r = 0; r < 4; ++r)
                sO[c * LDO2 + 64 * w + 16 * qt + 4 * quad + r] = acc_o[qt][ct][r];
        }
    __syncthreads();
    const int mw = tid & 31, cg = tid >> 5;   // mw: s-chunk (4 wide), cg: 0..3
    if (PARTIAL) {
        unsigned short* Op = Obf + (size_t)h * 8 * DIM * SEQ;
        #pragma unroll
        for (int cc = 0; cc < 16; ++cc) {
            const int c = cg + 4 * cc;
            const f32x4 v = *(const f32x4*)(sO + c * LDO2 + 4 * mw);
            *(ushort4*)(Op + ((size_t)b * DIM + c) * SEQ + s0 + 4 * mw) =
                make_ushort4(f2bf(v.x), f2bf(v.y), f2bf(v.z), f2bf(v.w));
        }
    } else {
        #pragma unroll
        for (int cc = 0; cc < 16; ++cc) {
            const int c = cg + 4 * cc;
            const f32x4 v = *(const f32x4*)(sO + c * LDO2 + 4 * mw);
            *(f32x4*)(Out + ((size_t)b * DIM + c) * SEQ + s0 + 4 * mw) = v;
        }
    }
}

__global__ __launch_bounds__(256) void combine4(const unsigned short* __restrict__ Obf,
                                                const float* __restrict__ Lp,
                                                float* __restrict__ Out) {
    const int gid = blockIdx.x * 256 + threadIdx.x;
    const size_t base = (size_t)gid * 4;
    const int s = (int)(base & 4095);
    const int b = (int)(base >> 18);
    f32x4 os = (f32x4){0.f, 0.f, 0.f, 0.f};
    f32x4 ls = (f32x4){0.f, 0.f, 0.f, 0.f};
    #pragma unroll
    for (int h = 0; h < 4; ++h) {
        const ushort4 o = *(const ushort4*)(Obf + (size_t)h * 2097152 + base);
        os[0] += bf2f(o.x); os[1] += bf2f(o.y); os[2] += bf2f(o.z); os[3] += bf2f(o.w);
        const f32x4 l = *(const f32x4*)(Lp + (size_t)h * 8 * SEQ + b * SEQ + s);
        #pragma unroll
        for (int i = 0; i < 4; ++i) ls[i] += l[i];
    }
    f32x4 o;
    #pragma unroll
    for (int i = 0; i < 4; ++i) o[i] = os[i] / ls[i];
    *(f32x4*)(Out + base) = o;
}

__global__ __launch_bounds__(256, 2) void attn_fallback(const float* __restrict__ X,
                                                        float* __restrict__ Out) {
    __shared__ __align__(16) unsigned char smem[27648];
    unsigned short* sK = (unsigned short*)smem;
    unsigned short* sV = (unsigned short*)(smem + 9216);
    unsigned short* sP = (unsigned short*)(smem + 18432);
    float*          sO = (float*)smem;
    const int tid  = threadIdx.x;
    const int lane = tid & 63;
    const int w    = tid >> 6;
    const int l15  = lane & 15;
    const int quad = lane >> 4;
    const int b  = blockIdx.y;
    const int s0 = blockIdx.x * 64;
    const float* Xb = X + (size_t)b * DIM * SEQ;
    const int mgrp = tid & 15;
    const int c0   = tid >> 4;

    for (int cc = 0; cc < 4; ++cc) {
        int c = c0 + 16 * cc;
        const f32x4 v = *(const f32x4*)(Xb + (size_t)c * SEQ + s0 + 4 * mgrp);
        sK[(4 * mgrp + 0) * LDB + c] = f2bf(v.x);
        sK[(4 * mgrp + 1) * LDB + c] = f2bf(v.y);
        sK[(4 * mgrp + 2) * LDB + c] = f2bf(v.z);
        sK[(4 * mgrp + 3) * LDB + c] = f2bf(v.w);
    }
    __syncthreads();
    short8 qf0, qf1;
    {
        const int row = 16 * w + l15;
        qf0 = *(const short8*)(sK + row * LDB + quad * 8);
        qf1 = *(const short8*)(sK + row * LDB + 32 + quad * 8);
    }
    __syncthreads();
    f32x4 acc_o[4];
    for (int ct = 0; ct < 4; ++ct) acc_o[ct] = (f32x4){0.f, 0.f, 0.f, 0.f};
    float m_i[4] = {-1e30f, -1e30f, -1e30f, -1e30f};
    float l_i[4] = {0.f, 0.f, 0.f, 0.f};
    for (int kt = 0; kt < SEQ / 64; ++kt) {
        const int m0 = kt * 64;
        for (int cc = 0; cc < 4; ++cc) {
            int c = c0 + 16 * cc;
            const f32x4 v = *(const f32x4*)(Xb + (size_t)c * SEQ + m0 + 4 * mgrp);
            unsigned short h0 = f2bf(v.x), h1 = f2bf(v.y), h2 = f2bf(v.z), h3 = f2bf(v.w);
            *(ushort4*)(sV + c * LDB + 4 * mgrp) = make_ushort4(h0, h1, h2, h3);
            sK[(4 * mgrp + 0) * LDB + c] = h0;
            sK[(4 * mgrp + 1) * LDB + c] = h1;
            sK[(4 * mgrp + 2) * LDB + c] = h2;
            sK[(4 * mgrp + 3) * LDB + c] = h3;
        }
        __syncthreads();
        short8 vf[2][4];
        for (int ks = 0; ks < 2; ++ks)
            for (int ct = 0; ct < 4; ++ct)
                vf[ks][ct] = *(const short8*)(sV + (16 * ct + l15) * LDB + ks * 32 + quad * 8);
        f32x4 acc_s[4];
        for (int mt = 0; mt < 4; ++mt) {
            const int row = 16 * mt + l15;
            const short8 kf0 = *(const short8*)(sK + row * LDB + quad * 8);
            const short8 kf1 = *(const short8*)(sK + row * LDB + 32 + quad * 8);
            f32x4 a = (f32x4){0.f, 0.f, 0.f, 0.f};
            a = __builtin_amdgcn_mfma_f32_16x16x32_bf16(qf0, kf0, a, 0, 0, 0);
            a = __builtin_amdgcn_mfma_f32_16x16x32_bf16(qf1, kf1, a, 0, 0, 0);
            acc_s[mt] = a;
        }
        float alpha[4];
        for (int r = 0; r < 4; ++r) {
            float mx = fmaxf(fmaxf(acc_s[0][r], acc_s[1][r]), fmaxf(acc_s[2][r], acc_s[3][r]));
            mx = fmaxf(mx, __shfl_xor(mx, 1));
            mx = fmaxf(mx, __shfl_xor(mx, 2));
            mx = fmaxf(mx, __shfl_xor(mx, 4));
            mx = fmaxf(mx, __shfl_xor(mx, 8));
            const float mnew = fmaxf(m_i[r], mx);
            alpha[r] = __expf(m_i[r] - mnew);
            m_i[r] = mnew;
        }
        float rowsum[4] = {0.f, 0.f, 0.f, 0.f};
        unsigned short pb[4][4];
        for (int mt = 0; mt < 4; ++mt)
            for (int r = 0; r < 4; ++r) {
                const float p = __expf(acc_s[mt][r] - m_i[r]);
                rowsum[r] += p;
                pb[mt][r] = f2bf(p);
            }
        for (int r = 0; r < 4; ++r) {
            float s = rowsum[r];
            s += __shfl_xor(s, 1);
            s += __shfl_xor(s, 2);
            s += __shfl_xor(s, 4);
            s += __shfl_xor(s, 8);
            l_i[r] = alpha[r] * l_i[r] + s;
        }
        for (int ct = 0; ct < 4; ++ct)
            for (int r = 0; r < 4; ++r)
                acc_o[ct][r] *= alpha[r];
        for (int mt = 0; mt < 4; ++mt)
            for (int r = 0; r < 4; ++r)
                sP[(16 * w + quad * 4 + r) * LDB + l15 + 16 * mt] = pb[mt][r];
        __syncthreads();
        const short8 pf0 = *(const short8*)(sP + (16 * w + l15) * LDB + quad * 8);
        const short8 pf1 = *(const short8*)(sP + (16 * w + l15) * LDB + 32 + quad * 8);
        for (int ct = 0; ct < 4; ++ct) {
            acc_o[ct] = __builtin_amdgcn_mfma_f32_16x16x32_bf16(pf0, vf[0][ct], acc_o[ct], 0, 0, 0);
            acc_o[ct] = __builtin_amdgcn_mfma_f32_16x16x32_bf16(pf1, vf[1][ct], acc_o[ct], 0, 0, 0);
        }
    }
    float inv[4];
    for (int r = 0; r < 4; ++r) inv[r] = 1.f / l_i[r];
    for (int ct = 0; ct < 4; ++ct) {
        const int c = 16 * ct + l15;
        for (int r = 0; r < 4; ++r)
            sO[c * LDO + 16 * w + quad * 4 + r] = acc_o[ct][r] * inv[r];
    }
    __syncthreads();
    for (int cc = 0; cc < 4; ++cc) {
        const int c = c0 + 16 * cc;
        const f32x4 v = *(const f32x4*)(sO + c * LDO + 4 * mgrp);
        *(f32x4*)(Out + (size_t)b * DIM * SEQ + (size_t)c * SEQ + s0 + 4 * mgrp) = v;
    }
}

extern "C" void kernel_launch(void* const* d_in, const int* in_sizes, int n_in,
                              void* d_out, int out_size, void* d_ws, size_t ws_size,
                              hipStream_t stream) {
    const float* X = (const float*)d_in[0];
    float* Out = (float*)d_out;
    const size_t elems = (size_t)8 * SEQ * DIM;               // 2M
    const size_t offVf    = elems * 2;                        // Kf 4MB
    const size_t offNorms = offVf + elems * 2;                // Vf 4MB -> 8MB
    const size_t offMaxP  = offNorms + (size_t)8 * SEQ * 4;   // +128KB
    const size_t offObf   = offMaxP + 8 * 64 * 4;             // +2KB
    const size_t offLp    = offObf + 4 * elems * 2;           // +16MB (4 bf16 slabs)
    const size_t need     = offLp + 4 * (size_t)8 * SEQ * 4;  // ~24.64MB (proven budget)

    if (ws_size >= need) {
        unsigned short* Kf = (unsigned short*)d_ws;
        unsigned short* Vf = (unsigned short*)((char*)d_ws + offVf);
        float* Norms   = (float*)((char*)d_ws + offNorms);
        float* MaxPart = (float*)((char*)d_ws + offMaxP);
        unsigned short* Obf = (unsigned short*)((char*)d_ws + offObf);
        float* Lp = (float*)((char*)d_ws + offLp);
        prepass4<<<dim3(64, 8), 256, 0, stream>>>(X, Kf, Vf, Norms, MaxPart);
        attn_split4<true><<<dim3(32, 8, 4), 128, 0, stream>>>(Kf, Vf, Norms, MaxPart,
                                                              Obf, Lp, nullptr, 32);
        combine4<<<(int)(elems / 1024), 256, 0, stream>>>(Obf, Lp, Out);
    } else {
        attn_fallback<<<dim3(64, 8), 256, 0, stream>>>(X, Out);
    }
}

// Round 14
// 104.805 us; speedup vs baseline: 3.4975x; 1.0205x over previous
//
#include <hip/hip_runtime.h>
#include <math.h>

// Non-local attention: X [8, 64, 64, 64] fp32.
// Per batch b: Q=K=V = X_b^T  [S=4096, D=64];  out = softmax(Q K^T) V, stored [b][c][s].
//
// R24: cross-iteration software pipeline (T15) on the R13 structure. 13 rounds
// established duration invariant to waves/SIMD, MFMA count, bytes, split depth,
// and load depth -- the ONE dependency never broken is S->exp->PV within a single
// iteration (in-order issue: wave stalls at exp until S-MFMA completes, matrix pipe
// idles through the VALU phase). This round pipelines one tile deep: each half
// issues S-MFMA(t+1) [matrix], then exp/pack(t) [VALU on ~600-cyc-old operands,
// zero stall], then PV(t) [matrix]. Two named states (aP/aC, vfP/vfC -- static
// indexing). The C-S bound moves from the MFMA C-init into the exp argument
// (exp2(a - mrow)), saving 12 VGPR. K/V stream indexing verified: no over-read.
// Retained from R13: barrier-free LDS-free loop, 64 Q rows/wave, per-wave global
// fragment loads (lane-contiguous 1KB per 16B-load), zero-movement P (k-slot<->key
// bijection q*8+j <-> 16*(j>>2)+4q+(j&3); Vf pre-permuted), XCD-pinned batch remap
// (b=gid&7), split-K x4 (niter 32), single-phase 34KB epilogue, combine over 4
// slabs, launch_bounds(128,2).
//
// Kf[b][tile][mt][ks][lane]: scaled bf16, lane(=quad*16+l15) holds
//   XbfT_scaled[tile*32+mt*16+l15][quad*8+32*ks .. +8]   (also serves Q fragments)
// Vf[b][tile][ct][lane][j]: unscaled bf16, element j at lane (l15,q) holds
//   XbfT[tile*32 + 16*(j>>2) + 4*q + (j&3)][16*ct + l15]   (permuted B-frag order)

#define SEQ 4096
#define DIM 64
#define LDB 72
#define LDO 68
#define LDO2 133
#define LDS2 68
#define QSCALE 1.2011224087864498f   // sqrt(log2(e))

typedef __attribute__((ext_vector_type(8))) short  short8;
typedef __attribute__((ext_vector_type(4))) float  f32x4;

__device__ __forceinline__ unsigned short f2bf(float f) {
    union { float f; unsigned int u; } x; x.f = f;
    unsigned int u = x.u + 0x7FFFu + ((x.u >> 16) & 1u);
    return (unsigned short)(u >> 16);
}
__device__ __forceinline__ float bf2f(unsigned short h) {
    union { unsigned int u; float f; } x; x.u = ((unsigned int)h) << 16; return x.f;
}
__device__ __forceinline__ float fast_exp2(float x) {
#if __has_builtin(__builtin_amdgcn_exp2f)
    return __builtin_amdgcn_exp2f(x);
#else
    float r;
    asm("v_exp_f32 %0, %1\n\ts_nop 0" : "=v"(r) : "v"(x));
    return r;
#endif
}
__device__ __forceinline__ float fast_rcp(float x) {
#if __has_builtin(__builtin_amdgcn_rcpf)
    return __builtin_amdgcn_rcpf(x);
#else
    return 1.f / x;
#endif
}

// ---------------- prepass: fragment-order bf16 arrays + scaled norms + max partials ----
__global__ __launch_bounds__(256) void prepass4(const float* __restrict__ X,
                                                unsigned short* __restrict__ Kf,
                                                unsigned short* __restrict__ Vf,
                                                float* __restrict__ Norms,
                                                float* __restrict__ MaxPart) {
    __shared__ __align__(16) unsigned short sT[64 * LDS2];    // scaled [m][c]
    __shared__ __align__(16) unsigned short sVu[64 * LDS2];   // unscaled [c][m]
    __shared__ float sRed[4];
    const int b = blockIdx.y, m0 = blockIdx.x * 64;
    const float* Xb = X + (size_t)b * DIM * SEQ;
    const int t = threadIdx.x, w = t >> 6;
    const int mw = t & 15, cg = t >> 4;

    #pragma unroll
    for (int cr = 0; cr < 4; ++cr) {
        const int c = cg * 4 + cr;
        const f32x4 v = *(const f32x4*)(Xb + (size_t)c * SEQ + m0 + 4 * mw);
        *(ushort4*)(sVu + c * LDS2 + 4 * mw) =
            make_ushort4(f2bf(v.x), f2bf(v.y), f2bf(v.z), f2bf(v.w));
        sT[(4 * mw + 0) * LDS2 + c] = f2bf(v.x * QSCALE);
        sT[(4 * mw + 1) * LDS2 + c] = f2bf(v.y * QSCALE);
        sT[(4 * mw + 2) * LDS2 + c] = f2bf(v.z * QSCALE);
        sT[(4 * mw + 3) * LDS2 + c] = f2bf(v.w * QSCALE);
    }
    __syncthreads();
    const int m = t >> 2, ck = t & 3;   // Kf mapping: key row m, dim-chunk pair ck

    // ---- Kf: row m, dim-chunks 2ck and 2ck+1 ----
    const short8 a0 = *(const short8*)(sT + m * LDS2 + ck * 16);
    const short8 a1 = *(const short8*)(sT + m * LDS2 + ck * 16 + 8);
    {
        const size_t base = (size_t)b * 262144 + (size_t)(m0 >> 5) * 2048;  // shorts
        #pragma unroll
        for (int j = 0; j < 2; ++j) {
            const int chunk = 2 * ck + j;
            const int tile = m >> 5, mt = (m >> 4) & 1;
            const int quad = chunk & 3, ks = chunk >> 2;
            const size_t off = base + (size_t)(tile * 4 + mt * 2 + ks) * 512
                                    + (size_t)(quad * 16 + (m & 15)) * 8;
            *(short8*)(Kf + off) = j ? a1 : a0;
        }
    }
    // ---- scaled row norm (from a0/a1), exact C-S bound on scaled scores ----
    float s = 0.f;
    #pragma unroll
    for (int i = 0; i < 8; ++i) {
        const float f0 = bf2f((unsigned short)a0[i]);
        const float f1 = bf2f((unsigned short)a1[i]);
        s += f0 * f0 + f1 * f1;
    }
    s += __shfl_xor(s, 1);
    s += __shfl_xor(s, 2);
    const float nm = sqrtf(s);
    if (ck == 0) Norms[(size_t)b * SEQ + m0 + m] = nm;

    // ---- Vf: permuted B-frag order, one contiguous 16B fragment per (tile,ct,lane) ----
    {
        const int ctv = (t >> 6) & 3, lv = t & 63;
        const int qv = lv >> 4, l15v = lv & 15;
        const int cidx = (16 * ctv + l15v) * LDS2;
        const size_t vbase = (size_t)b * 262144 + (size_t)(m0 >> 5) * 2048
                           + (size_t)ctv * 512 + (size_t)lv * 8;
        #pragma unroll
        for (int tl = 0; tl < 2; ++tl) {
            const ushort4 g0 = *(const ushort4*)(sVu + cidx + tl * 32 + 4 * qv);
            const ushort4 g1 = *(const ushort4*)(sVu + cidx + tl * 32 + 16 + 4 * qv);
            union { ushort4 g[2]; short8 v; } cat;
            cat.g[0] = g0; cat.g[1] = g1;
            *(short8*)(Vf + vbase + (size_t)tl * 2048) = cat.v;
        }
    }

    float mx = nm;
    #pragma unroll
    for (int d = 4; d < 64; d <<= 1) mx = fmaxf(mx, __shfl_xor(mx, d));
    if ((t & 63) == 0) sRed[w] = mx;
    __syncthreads();
    if (t == 0)
        MaxPart[b * 64 + blockIdx.x] =
            fmaxf(fmaxf(sRed[0], sRed[1]), fmaxf(sRed[2], sRed[3]));
}

// ---- macros for the pipelined flash loop (kp/vp/qf/mneg/acc_o/lp4 in scope) ----
#define LOADK(DST)                                                                 \
    {                                                                              \
        _Pragma("unroll")                                                          \
        for (int mt_ = 0; mt_ < 2; ++mt_) {                                        \
            _Pragma("unroll")                                                      \
            for (int ks_ = 0; ks_ < 2; ++ks_)                                      \
                DST[mt_][ks_] = *(const short8*)(kp + (mt_ * 2 + ks_) * 512);      \
        }                                                                          \
    }

#define LOADV(DST)                                                                 \
    {                                                                              \
        _Pragma("unroll")                                                          \
        for (int ct_ = 0; ct_ < 4; ++ct_)                                          \
            DST[ct_] = *(const short8*)(vp + ct_ * 512);                           \
    }

// S-MFMAs for one 32-key tile into ADST (C-in = 0; bound applied at exp time).
#define SMFMA(KF, ADST)                                                            \
    {                                                                              \
        _Pragma("unroll")                                                          \
        for (int qt_ = 0; qt_ < 4; ++qt_) {                                        \
            _Pragma("unroll")                                                      \
            for (int mt_ = 0; mt_ < 2; ++mt_) {                                    \
                f32x4 s_ = (f32x4){0.f, 0.f, 0.f, 0.f};                            \
                s_ = __builtin_amdgcn_mfma_f32_16x16x32_bf16(KF[mt_][0], qf[qt_][0], s_, 0, 0, 0); \
                s_ = __builtin_amdgcn_mfma_f32_16x16x32_bf16(KF[mt_][1], qf[qt_][1], s_, 0, 0, 0); \
                ADST[qt_][mt_] = s_;                                               \
            }                                                                      \
        }                                                                          \
    }

// exp/pack + PV for one tile whose S results (ASRC) are a full pipeline stage old.
#define EXPPV(ASRC, VF)                                                            \
    {                                                                              \
        short8 pa_[4];                                                             \
        _Pragma("unroll")                                                          \
        for (int qt_ = 0; qt_ < 4; ++qt_) {                                        \
            union { unsigned u[4]; short8 v; } pk_;                                \
            _Pragma("unroll")                                                      \
            for (int mt_ = 0; mt_ < 2; ++mt_) {                                    \
                const float p0_ = fast_exp2(ASRC[qt_][mt_][0] + mneg[qt_]);        \
                const float p1_ = fast_exp2(ASRC[qt_][mt_][1] + mneg[qt_]);        \
                const float p2_ = fast_exp2(ASRC[qt_][mt_][2] + mneg[qt_]);        \
                const float p3_ = fast_exp2(ASRC[qt_][mt_][3] + mneg[qt_]);        \
                lp4[qt_] += (f32x4){p0_, p1_, p2_, p3_};                           \
                pk_.u[2 * mt_ + 0] = __builtin_amdgcn_perm(__float_as_uint(p1_), __float_as_uint(p0_), 0x07060302u); \
                pk_.u[2 * mt_ + 1] = __builtin_amdgcn_perm(__float_as_uint(p3_), __float_as_uint(p2_), 0x07060302u); \
            }                                                                      \
            pa_[qt_] = pk_.v;                                                      \
        }                                                                          \
        _Pragma("unroll")                                                          \
        for (int qt_ = 0; qt_ < 4; ++qt_) {                                        \
            _Pragma("unroll")                                                      \
            for (int ct_ = 0; ct_ < 4; ++ct_)                                      \
                acc_o[qt_][ct_] = __builtin_amdgcn_mfma_f32_16x16x32_bf16(pa_[qt_], VF[ct_], acc_o[qt_][ct_], 0, 0, 0); \
        }                                                                          \
    }

// Flash kernel: 2 waves x 64 Q rows, split-K x4. Fragment-order global K/V,
// LDS-free, barrier-free, one-tile-deep software pipeline (S(t+1) || exp/PV(t)).
template <bool PARTIAL>
__global__ __launch_bounds__(128, 2) void attn_split4(const unsigned short* __restrict__ Kf,
                                                      const unsigned short* __restrict__ Vf,
                                                      const float* __restrict__ Norms,
                                                      const float* __restrict__ MaxPart,
                                                      unsigned short* __restrict__ Obf,  // PARTIAL
                                                      float* __restrict__ Lbase,         // PARTIAL
                                                      float* __restrict__ Out,           // !PARTIAL
                                                      int niter) {
    __shared__ __align__(16) float sO[64 * LDO2];   // epilogue staging only (34048 B)

    const int tid  = threadIdx.x;
    const int lane = tid & 63;
    const int w    = tid >> 6;
    const int l15  = lane & 15;
    const int quad = lane >> 4;

    // XCD-pinned work remap: dispatch round-robins linear wg id across the 8 XCDs,
    // so gid&7 == XCD. Assign batch = gid&7 so each XCD streams exactly one batch's
    // 1MB K/V slab (L2-resident). Pure work remap -- placement only affects speed.
    const int gid  = blockIdx.x + 32 * (blockIdx.y + 8 * blockIdx.z);
    const int b    = gid & 7;
    const int rest = gid >> 3;             // 0..127
    const int s0   = (rest & 31) * 128;    // 128 Q rows per block
    const int h    = rest >> 5;            // 0..3 split-K quarter
    const int kt0  = h * niter;
    const unsigned short* Kfb = Kf + (size_t)b * 262144;
    const unsigned short* Vfb = Vf + (size_t)b * 262144;

    float mxn = MaxPart[b * 64 + lane];
    #pragma unroll
    for (int d = 1; d < 64; d <<= 1) mxn = fmaxf(mxn, __shfl_xor(mxn, d));

    // Q frags from Kf (scaled): wave w owns rows s0+64w .. +63 (qt = 0..3)
    short8 qf[4][2];
    float  mneg[4];
    const int qtile = (s0 + 64 * w) >> 5;
    #pragma unroll
    for (int qt = 0; qt < 4; ++qt) {
        #pragma unroll
        for (int ks = 0; ks < 2; ++ks)
            qf[qt][ks] = *(const short8*)(Kfb
                + (size_t)((qtile + (qt >> 1)) * 4 + (qt & 1) * 2 + ks) * 512 + lane * 8);
        mneg[qt] = -(Norms[(size_t)b * SEQ + s0 + 64 * w + 16 * qt + l15] * mxn);
    }

    f32x4 acc_o[4][4];
    #pragma unroll
    for (int qt = 0; qt < 4; ++qt)
        #pragma unroll
        for (int ct = 0; ct < 4; ++ct) acc_o[qt][ct] = (f32x4){0.f, 0.f, 0.f, 0.f};
    f32x4 lp4[4];
    #pragma unroll
    for (int qt = 0; qt < 4; ++qt) lp4[qt] = (f32x4){0.f, 0.f, 0.f, 0.f};

    // ---- fragment stream pointers (lane-contiguous 1KB per 16B-load) ----
    const unsigned short* kp = Kfb + (size_t)kt0 * 2048 + lane * 8;
    const unsigned short* vp = Vfb + (size_t)kt0 * 2048 + lane * 8;

    short8 kA[2][2], kB[2][2];
    short8 vfP[4], vfC[4];
    f32x4  aP[4][2], aC[4][2];

    // ---- prologue: tile 0 S in flight, K tile 1 loaded ----
    LOADK(kA); kp += 2048;                 // K tile 0
    LOADV(vfP); vp += 2048;                // V tile 0
    LOADK(kB); kp += 2048;                 // K tile 1
    SMFMA(kA, aP);                         // S tile 0

    for (int it = 0; it < niter - 2; it += 2) {
        LOADV(vfC); vp += 2048;            // V tile it+1
        LOADK(kA); kp += 2048;             // K tile it+2
        SMFMA(kB, aC);                     // S tile it+1 (matrix)
        EXPPV(aP, vfP);                    // finish tile it (VALU on old data + PV)
        LOADV(vfP); vp += 2048;            // V tile it+2
        LOADK(kB); kp += 2048;             // K tile it+3 (last pass: tile niter-1)
        SMFMA(kA, aP);                     // S tile it+2
        EXPPV(aC, vfC);                    // finish tile it+1
    }
    // after loop: aP = S(niter-2), vfP = V(niter-2), kB = K(niter-1). No over-read.
    LOADV(vfC); vp += 2048;                // V tile niter-1
    SMFMA(kB, aC);                         // S tile niter-1
    EXPPV(aP, vfP);                        // tile niter-2
    EXPPV(aC, vfC);                        // tile niter-1

    float lp[4];
    #pragma unroll
    for (int qt = 0; qt < 4; ++qt) {
        lp[qt] = (lp4[qt][0] + lp4[qt][1]) + (lp4[qt][2] + lp4[qt][3]);
        lp[qt] += __shfl_xor(lp[qt], 16);
        lp[qt] += __shfl_xor(lp[qt], 32);
    }

    if (PARTIAL) {
        if (quad == 0) {
            #pragma unroll
            for (int qt = 0; qt < 4; ++qt)
                (Lbase + (size_t)h * 8 * SEQ)[(size_t)b * SEQ + s0 + 64 * w + 16 * qt + l15] = lp[qt];
        }
    } else {
        #pragma unroll
        for (int qt = 0; qt < 4; ++qt) {
            float inv[4];
            #pragma unroll
            for (int r = 0; r < 4; ++r) inv[r] = fast_rcp(__shfl(lp[qt], 4 * quad + r));
            #pragma unroll
            for (int ct = 0; ct < 4; ++ct)
                #pragma unroll
                for (int r = 0; r < 4; ++r) acc_o[qt][ct][r] *= inv[r];
        }
    }

    #pragma unroll
    for (int qt = 0; qt < 4; ++qt)
        #pragma unroll
        for (int ct = 0; ct < 4; ++ct) {
            const int c = 16 * ct + l15;
            #pragma unroll
            for (int r = 0; r < 4; ++r)
                sO[c * LDO2 + 64 * w + 16 * qt + 4 * quad + r] = acc_o[qt][ct][r];
        }
    __syncthreads();
    const int mw = tid & 31, cg = tid >> 5;   // mw: s-chunk (4 wide), cg: 0..3
    if (PARTIAL) {
        unsigned short* Op = Obf + (size_t)h * 8 * DIM * SEQ;
        #pragma unroll
        for (int cc = 0; cc < 16; ++cc) {
            const int c = cg + 4 * cc;
            const f32x4 v = *(const f32x4*)(sO + c * LDO2 + 4 * mw);
            *(ushort4*)(Op + ((size_t)b * DIM + c) * SEQ + s0 + 4 * mw) =
                make_ushort4(f2bf(v.x), f2bf(v.y), f2bf(v.z), f2bf(v.w));
        }
    } else {
        #pragma unroll
        for (int cc = 0; cc < 16; ++cc) {
            const int c = cg + 4 * cc;
            const f32x4 v = *(const f32x4*)(sO + c * LDO2 + 4 * mw);
            *(f32x4*)(Out + ((size_t)b * DIM + c) * SEQ + s0 + 4 * mw) = v;
        }
    }
}

__global__ __launch_bounds__(256) void combine4(const unsigned short* __restrict__ Obf,
                                                const float* __restrict__ Lp,
                                                float* __restrict__ Out) {
    const int gid = blockIdx.x * 256 + threadIdx.x;
    const size_t base = (size_t)gid * 4;
    const int s = (int)(base & 4095);
    const int b = (int)(base >> 18);
    f32x4 os = (f32x4){0.f, 0.f, 0.f, 0.f};
    f32x4 ls = (f32x4){0.f, 0.f, 0.f, 0.f};
    #pragma unroll
    for (int h = 0; h < 4; ++h) {
        const ushort4 o = *(const ushort4*)(Obf + (size_t)h * 2097152 + base);
        os[0] += bf2f(o.x); os[1] += bf2f(o.y); os[2] += bf2f(o.z); os[3] += bf2f(o.w);
        const f32x4 l = *(const f32x4*)(Lp + (size_t)h * 8 * SEQ + b * SEQ + s);
        #pragma unroll
        for (int i = 0; i < 4; ++i) ls[i] += l[i];
    }
    f32x4 o;
    #pragma unroll
    for (int i = 0; i < 4; ++i) o[i] = os[i] / ls[i];
    *(f32x4*)(Out + base) = o;
}

__global__ __launch_bounds__(256, 2) void attn_fallback(const float* __restrict__ X,
                                                        float* __restrict__ Out) {
    __shared__ __align__(16) unsigned char smem[27648];
    unsigned short* sK = (unsigned short*)smem;
    unsigned short* sV = (unsigned short*)(smem + 9216);
    unsigned short* sP = (unsigned short*)(smem + 18432);
    float*          sO = (float*)smem;
    const int tid  = threadIdx.x;
    const int lane = tid & 63;
    const int w    = tid >> 6;
    const int l15  = lane & 15;
    const int quad = lane >> 4;
    const int b  = blockIdx.y;
    const int s0 = blockIdx.x * 64;
    const float* Xb = X + (size_t)b * DIM * SEQ;
    const int mgrp = tid & 15;
    const int c0   = tid >> 4;

    for (int cc = 0; cc < 4; ++cc) {
        int c = c0 + 16 * cc;
        const f32x4 v = *(const f32x4*)(Xb + (size_t)c * SEQ + s0 + 4 * mgrp);
        sK[(4 * mgrp + 0) * LDB + c] = f2bf(v.x);
        sK[(4 * mgrp + 1) * LDB + c] = f2bf(v.y);
        sK[(4 * mgrp + 2) * LDB + c] = f2bf(v.z);
        sK[(4 * mgrp + 3) * LDB + c] = f2bf(v.w);
    }
    __syncthreads();
    short8 qf0, qf1;
    {
        const int row = 16 * w + l15;
        qf0 = *(const short8*)(sK + row * LDB + quad * 8);
        qf1 = *(const short8*)(sK + row * LDB + 32 + quad * 8);
    }
    __syncthreads();
    f32x4 acc_o[4];
    for (int ct = 0; ct < 4; ++ct) acc_o[ct] = (f32x4){0.f, 0.f, 0.f, 0.f};
    float m_i[4] = {-1e30f, -1e30f, -1e30f, -1e30f};
    float l_i[4] = {0.f, 0.f, 0.f, 0.f};
    for (int kt = 0; kt < SEQ / 64; ++kt) {
        const int m0 = kt * 64;
        for (int cc = 0; cc < 4; ++cc) {
            int c = c0 + 16 * cc;
            const f32x4 v = *(const f32x4*)(Xb + (size_t)c * SEQ + m0 + 4 * mgrp);
            unsigned short h0 = f2bf(v.x), h1 = f2bf(v.y), h2 = f2bf(v.z), h3 = f2bf(v.w);
            *(ushort4*)(sV + c * LDB + 4 * mgrp) = make_ushort4(h0, h1, h2, h3);
            sK[(4 * mgrp + 0) * LDB + c] = h0;
            sK[(4 * mgrp + 1) * LDB + c] = h1;
            sK[(4 * mgrp + 2) * LDB + c] = h2;
            sK[(4 * mgrp + 3) * LDB + c] = h3;
        }
        __syncthreads();
        short8 vf[2][4];
        for (int ks = 0; ks < 2; ++ks)
            for (int ct = 0; ct < 4; ++ct)
                vf[ks][ct] = *(const short8*)(sV + (16 * ct + l15) * LDB + ks * 32 + quad * 8);
        f32x4 acc_s[4];
        for (int mt = 0; mt < 4; ++mt) {
            const int row = 16 * mt + l15;
            const short8 kf0 = *(const short8*)(sK + row * LDB + quad * 8);
            const short8 kf1 = *(const short8*)(sK + row * LDB + 32 + quad * 8);
            f32x4 a = (f32x4){0.f, 0.f, 0.f, 0.f};
            a = __builtin_amdgcn_mfma_f32_16x16x32_bf16(qf0, kf0, a, 0, 0, 0);
            a = __builtin_amdgcn_mfma_f32_16x16x32_bf16(qf1, kf1, a, 0, 0, 0);
            acc_s[mt] = a;
        }
        float alpha[4];
        for (int r = 0; r < 4; ++r) {
            float mx = fmaxf(fmaxf(acc_s[0][r], acc_s[1][r]), fmaxf(acc_s[2][r], acc_s[3][r]));
            mx = fmaxf(mx, __shfl_xor(mx, 1));
            mx = fmaxf(mx, __shfl_xor(mx, 2));
            mx = fmaxf(mx, __shfl_xor(mx, 4));
            mx = fmaxf(mx, __shfl_xor(mx, 8));
            const float mnew = fmaxf(m_i[r], mx);
            alpha[r] = __expf(m_i[r] - mnew);
            m_i[r] = mnew;
        }
        float rowsum[4] = {0.f, 0.f, 0.f, 0.f};
        unsigned short pb[4][4];
        for (int mt = 0; mt < 4; ++mt)
            for (int r = 0; r < 4; ++r) {
                const float p = __expf(acc_s[mt][r] - m_i[r]);
                rowsum[r] += p;
                pb[mt][r] = f2bf(p);
            }
        for (int r = 0; r < 4; ++r) {
            float s = rowsum[r];
            s += __shfl_xor(s, 1);
            s += __shfl_xor(s, 2);
            s += __shfl_xor(s, 4);
            s += __shfl_xor(s, 8);
            l_i[r] = alpha[r] * l_i[r] + s;
        }
        for (int ct = 0; ct < 4; ++ct)
            for (int r = 0; r < 4; ++r)
                acc_o[ct][r] *= alpha[r];
        for (int mt = 0; mt < 4; ++mt)
            for (int r = 0; r < 4; ++r)
                sP[(16 * w + quad * 4 + r) * LDB + l15 + 16 * mt] = pb[mt][r];
        __syncthreads();
        const short8 pf0 = *(const short8*)(sP + (16 * w + l15) * LDB + quad * 8);
        const short8 pf1 = *(const short8*)(sP + (16 * w + l15) * LDB + 32 + quad * 8);
        for (int ct = 0; ct < 4; ++ct) {
            acc_o[ct] = __builtin_amdgcn_mfma_f32_16x16x32_bf16(pf0, vf[0][ct], acc_o[ct], 0, 0, 0);
            acc_o[ct] = __builtin_amdgcn_mfma_f32_16x16x32_bf16(pf1, vf[1][ct], acc_o[ct], 0, 0, 0);
        }
    }
    float inv[4];
    for (int r = 0; r < 4; ++r) inv[r] = 1.f / l_i[r];
    for (int ct = 0; ct < 4; ++ct) {
        const int c = 16 * ct + l15;
        for (int r = 0; r < 4; ++r)
            sO[c * LDO + 16 * w + quad * 4 + r] = acc_o[ct][r] * inv[r];
    }
    __syncthreads();
    for (int cc = 0; cc < 4; ++cc) {
        const int c = c0 + 16 * cc;
        const f32x4 v = *(const f32x4*)(sO + c * LDO + 4 * mgrp);
        *(f32x4*)(Out + (size_t)b * DIM * SEQ + (size_t)c * SEQ + s0 + 4 * mgrp) = v;
    }
}

extern "C" void kernel_launch(void* const* d_in, const int* in_sizes, int n_in,
                              void* d_out, int out_size, void* d_ws, size_t ws_size,
                              hipStream_t stream) {
    const float* X = (const float*)d_in[0];
    float* Out = (float*)d_out;
    const size_t elems = (size_t)8 * SEQ * DIM;               // 2M
    const size_t offVf    = elems * 2;                        // Kf 4MB
    const size_t offNorms = offVf + elems * 2;                // Vf 4MB -> 8MB
    const size_t offMaxP  = offNorms + (size_t)8 * SEQ * 4;   // +128KB
    const size_t offObf   = offMaxP + 8 * 64 * 4;             // +2KB
    const size_t offLp    = offObf + 4 * elems * 2;           // +16MB (4 bf16 slabs)
    const size_t need     = offLp + 4 * (size_t)8 * SEQ * 4;  // ~24.64MB (proven budget)

    if (ws_size >= need) {
        unsigned short* Kf = (unsigned short*)d_ws;
        unsigned short* Vf = (unsigned short*)((char*)d_ws + offVf);
        float* Norms   = (float*)((char*)d_ws + offNorms);
        float* MaxPart = (float*)((char*)d_ws + offMaxP);
        unsigned short* Obf = (unsigned short*)((char*)d_ws + offObf);
        float* Lp = (float*)((char*)d_ws + offLp);
        prepass4<<<dim3(64, 8), 256, 0, stream>>>(X, Kf, Vf, Norms, MaxPart);
        attn_split4<true><<<dim3(32, 8, 4), 128, 0, stream>>>(Kf, Vf, Norms, MaxPart,
                                                              Obf, Lp, nullptr, 32);
        combine4<<<(int)(elems / 1024), 256, 0, stream>>>(Obf, Lp, Out);
    } else {
        attn_fallback<<<dim3(64, 8), 256, 0, stream>>>(X, Out);
    }
}